// Round 14
// baseline (811.510 us; speedup 1.0000x reference)
//
#include <hip/hip_runtime.h>
#include <hip/hip_bf16.h>

#define DD 128
#define BN_EPS 1e-5f
#define NBLK 160   // blocks for loss partial kernel
#define ALD 264    // LDS row stride (bf16) for K=256
#define PLD 136    // LDS row stride (bf16) for K=128

typedef __hip_bfloat16 bf16;
typedef __attribute__((ext_vector_type(8))) short short8;
typedef __attribute__((ext_vector_type(4))) float f32x4;

__device__ __forceinline__ float b2f(unsigned short u) {
    union { float f; unsigned int i; } x; x.i = ((unsigned int)u) << 16; return x.f;
}
__device__ __forceinline__ unsigned short f2bs(float v) {
    bf16 h = __float2bfloat16(v);
    return *(unsigned short*)&h;
}

// ---- dtype detect: flag=1 if d_in[0] is packed bf16, 0 if f32 ----
__global__ void detect_dtype(const unsigned int* __restrict__ x, int* __restrict__ flag) {
    __shared__ int s[256];
    int t = threadIdx.x;
    unsigned int u = x[t];
    unsigned int e = (u >> 7) & 0xFFu;
    s[t] = ((e >= 90u && e <= 140u) || ((u & 0xFFFFu) == 0u)) ? 1 : 0;
    __syncthreads();
    for (int off = 128; off > 0; off >>= 1) { if (t < off) s[t] += s[t + off]; __syncthreads(); }
    if (t == 0) *flag = (s[0] >= 128) ? 1 : 0;
}

// ---- fused weight conversion ----
struct CvtTable {
    const void* src[20];
    int off[20];
    int n[20];
    int total;
};
__global__ __launch_bounds__(256) void cvt_all(CvtTable tab, float* __restrict__ wsf,
                                               const int* __restrict__ flagp) {
    int i = blockIdx.x * 256 + threadIdx.x;
    if (i >= tab.total) return;
    int k = 0;
    while (i >= tab.n[k]) { i -= tab.n[k]; ++k; }
    float v;
    if (*flagp) v = b2f(((const unsigned short*)tab.src[k])[i]);
    else        v = ((const float*)tab.src[k])[i];
    wsf[tab.off[k] + i] = v;
}

// ---- fused MFMA B-fragment builder (5 tables) ----
struct WfAll {
    const float* W1[5];
    const float* W2[5];
    unsigned short* dst[5];
    int KS[5];
    int start[5];
    int total;
};
__global__ __launch_bounds__(256) void wfrag_all(WfAll w) {
    int t = blockIdx.x * 256 + threadIdx.x;
    if (t >= w.total) return;
    int k = 0;
    while (k < 4 && t >= w.start[k + 1]) ++k;
    int lt = t - w.start[k];
    int KS = w.KS[k];
    int lane = lt & 63;
    int ks = (lt >> 6) % KS;
    int ct = lt / (KS * 64);
    int n = ct * 16 + (lane & 15);
    unsigned short v[8];
#pragma unroll
    for (int j = 0; j < 8; ++j) {
        int kk = ks * 32 + ((lane >> 4) & 3) * 8 + j;
        float wv = (kk < 128) ? w.W1[k][kk * DD + n] : w.W2[k][(kk - 128) * DD + n];
        v[j] = f2bs(wv);
    }
    *(uint4*)&w.dst[k][(size_t)lt * 8] = *(uint4*)v;
}

// ---- CSR: windowed histogram over concatenated dst space ----
__global__ __launch_bounds__(256) void hist_win(
    const int* __restrict__ d0, int e0, const int* __restrict__ d1, int e1,
    const int* __restrict__ d2, int e2, int* __restrict__ hist) {
    int stride = gridDim.x * 256;
    int t0 = blockIdx.x * 256 + threadIdx.x;
    for (int w = 0; w < 4; ++w) {
        int dlo = w * 12500, dhi = dlo + 12500;
        for (int e = t0; e < e0; e += stride) {
            int d = d0[e];
            if (d >= dlo && d < dhi) atomicAdd(&hist[d], 1);
        }
    }
    for (int e = t0; e < e1; e += stride) atomicAdd(&hist[50000 + d1[e]], 1);
    for (int e = t0; e < e2; e += stride) atomicAdd(&hist[75000 + d2[e]], 1);
}

// ---- hierarchical exclusive scan ----
__global__ __launch_bounds__(256) void scan_bsum(const int* __restrict__ cnt, int n,
                                                 int* __restrict__ bsums) {
    __shared__ int sm[256];
    int t = threadIdx.x, b = blockIdx.x;
    int i4 = b * 256 + t;
    int local = 0;
    if (i4 * 4 < n) { int4 v = ((const int4*)cnt)[i4]; local = v.x + v.y + v.z + v.w; }
    sm[t] = local;
    __syncthreads();
    for (int off = 128; off > 0; off >>= 1) { if (t < off) sm[t] += sm[t + off]; __syncthreads(); }
    if (t == 0) bsums[b] = sm[0];
}
__global__ void scan_bscan(int* __restrict__ bsums, int nb, int* __restrict__ rowptr_n) {
    __shared__ int wsum[4];
    int t = threadIdx.x, lane = t & 63, w = t >> 6;
    int v = (t < nb) ? bsums[t] : 0;
    int inc = v;
    for (int off = 1; off < 64; off <<= 1) {
        int u = __shfl_up(inc, off, 64);
        if (lane >= off) inc += u;
    }
    if (lane == 63) wsum[w] = inc;
    __syncthreads();
    int wo = 0;
    for (int i = 0; i < w; ++i) wo += wsum[i];
    if (t < nb) bsums[t] = wo + inc - v;
    if (t == 255) *rowptr_n = wo + inc;
}
__global__ __launch_bounds__(256) void scan_apply(const int* __restrict__ cnt, int n,
                                                  const int* __restrict__ bsums,
                                                  int* __restrict__ rowptr) {
    __shared__ int wsum[4];
    int t = threadIdx.x, b = blockIdx.x, lane = t & 63, w = t >> 6;
    int i4 = b * 256 + t;
    int4 v = {0, 0, 0, 0};
    bool valid = (i4 * 4 < n);
    if (valid) v = ((const int4*)cnt)[i4];
    int local = v.x + v.y + v.z + v.w;
    int inc = local;
    for (int off = 1; off < 64; off <<= 1) {
        int u = __shfl_up(inc, off, 64);
        if (lane >= off) inc += u;
    }
    if (lane == 63) wsum[w] = inc;
    __syncthreads();
    int wo = 0;
    for (int i = 0; i < w; ++i) wo += wsum[i];
    if (valid) {
        int acc = bsums[b] + wo + inc - local;
        int base = i4 * 4;
        rowptr[base + 0] = acc; acc += v.x;
        rowptr[base + 1] = acc; acc += v.y;
        rowptr[base + 2] = acc; acc += v.z;
        rowptr[base + 3] = acc;
    }
}

// ---- CSR fill, windowed by dst range ----
__global__ __launch_bounds__(256) void csr_fill_win(
    const int* __restrict__ s0, const int* __restrict__ d0, int e0,
    const int* __restrict__ s1, const int* __restrict__ d1, int e1,
    const int* __restrict__ s2, const int* __restrict__ d2, int e2,
    const int* __restrict__ rpAll, int* __restrict__ cur, int* __restrict__ eid) {
    int stride = gridDim.x * 256;
    int t0 = blockIdx.x * 256 + threadIdx.x;
    for (int w = 0; w < 4; ++w) {
        int dlo = w * 12500, dhi = dlo + 12500;
        for (int e = t0; e < e0; e += stride) {
            int d = d0[e];
            if (d >= dlo && d < dhi)
                eid[rpAll[d] + atomicAdd(&cur[d], 1)] = s0[e];
        }
    }
    for (int e = t0; e < e1; e += stride) {
        int gd = 50000 + d1[e];
        eid[rpAll[gd] + atomicAdd(&cur[gd], 1)] = s1[e];
    }
    for (int e = t0; e < e2; e += stride) {
        int gd = 75000 + d2[e];
        eid[rpAll[gd] + atomicAdd(&cur[gd], 1)] = s2[e];
    }
}

// ---- fused SAGE layer: gather-mean + MFMA GEMM, both halves in one grid ----
// Block = 64 rows. Wave w owns rows w*16..w*16+15: stages A1 (self, optional BN fold),
// gathers neighbor-mean into A2 cols, then MFMA — all wave-local (no barrier).
struct HalfArgs {
    const void* base;        // feature rows (x or H), bf16 unless flagp says f32
    const int* perm;         // optional row remap (L0 negative pass)
    const float* sc;         // optional BN fold scale (per column)
    const float* sh;         // optional BN fold shift
    unsigned short* out;     // bf16 output rows
    float* PS;               // optional per-block column sums
    float* PQ;               // optional per-block column sumsq
};
__global__ __launch_bounds__(256) void sage_layer(
    HalfArgs hP, HalfArgs hN, const int* __restrict__ flagp,
    const int* __restrict__ rowptr, const int* __restrict__ eid,
    const uint4* __restrict__ wfrag, const float* __restrict__ bias,
    int Nh, int nbHalf)
{
    __shared__ unsigned short As[64 * ALD];
    __shared__ float sds[256];
    const int tid = threadIdx.x;
    const int half = blockIdx.x / nbHalf;
    const int rb = (blockIdx.x % nbHalf) * 64;
    const HalfArgs H = half ? hN : hP;
    const int abf = flagp ? *flagp : 1;
    const bool bn = (H.sc != nullptr);
    const bool doStats = (H.PS != nullptr);

    // ---- A1 staging: thread covers row tid>>2, 32 cols at (tid&3)*32 ----
    {
        int r = tid >> 2, cs = (tid & 3) * 32;
        int gr = rb + r;
        unsigned short* dst = &As[r * ALD + cs];
        if (gr < Nh) {
            int ar = H.perm ? H.perm[gr] : gr;
            if (abf) {
                const unsigned short* s = (const unsigned short*)H.base + (size_t)ar * DD + cs;
                if (bn) {
#pragma unroll
                    for (int i = 0; i < 32; ++i) {
                        float v = b2f(s[i]);
                        v = fmaxf(H.sc[cs + i] * v + H.sh[cs + i], 0.0f);
                        dst[i] = f2bs(v);
                    }
                } else {
                    const uint4* sv = (const uint4*)s;
                    uint4* dv = (uint4*)dst;
#pragma unroll
                    for (int i = 0; i < 4; ++i) dv[i] = sv[i];
                }
            } else {
                const float* s = (const float*)H.base + (size_t)ar * DD + cs;
#pragma unroll
                for (int i = 0; i < 32; ++i) dst[i] = f2bs(s[i]);
            }
        } else {
            uint4 z = {0, 0, 0, 0};
            uint4* dv = (uint4*)dst;
#pragma unroll
            for (int i = 0; i < 4; ++i) dv[i] = z;
        }
    }

    const int w = tid >> 6, lane = tid & 63;

    // ---- A2 gather: wave w covers its own rows; lane covers 2 cols ----
    float c0 = 1.0f, c1 = 1.0f, h0 = 0.0f, h1 = 0.0f;
    if (bn) { c0 = H.sc[lane * 2]; c1 = H.sc[lane * 2 + 1];
              h0 = H.sh[lane * 2]; h1 = H.sh[lane * 2 + 1]; }
#define XF0(v) (bn ? fmaxf(c0 * (v) + h0, 0.0f) : (v))
#define XF1(v) (bn ? fmaxf(c1 * (v) + h1, 0.0f) : (v))
    for (int j = 0; j < 16; ++j) {
        int r = w * 16 + j;
        int d = rb + r;
        unsigned short* dst2 = &As[r * ALD + 128 + lane * 2];
        if (d >= Nh) { ushort2 z = {0, 0}; *(ushort2*)dst2 = z; continue; }
        int i0 = rowptr[d], i1 = rowptr[d + 1];
        float a0x = 0, a0y = 0, a1x = 0, a1y = 0, a2x = 0, a2y = 0, a3x = 0, a3y = 0;
        int i = i0;
        if (abf) {
            const unsigned short* h = (const unsigned short*)H.base;
            for (; i + 4 <= i1; i += 4) {
                int s0 = eid[i], s1 = eid[i + 1], s2 = eid[i + 2], s3 = eid[i + 3];
                if (H.perm) { s0 = H.perm[s0]; s1 = H.perm[s1]; s2 = H.perm[s2]; s3 = H.perm[s3]; }
                ushort2 v0 = *(const ushort2*)&h[(size_t)s0 * DD + lane * 2];
                ushort2 v1 = *(const ushort2*)&h[(size_t)s1 * DD + lane * 2];
                ushort2 v2 = *(const ushort2*)&h[(size_t)s2 * DD + lane * 2];
                ushort2 v3 = *(const ushort2*)&h[(size_t)s3 * DD + lane * 2];
                a0x += XF0(b2f(v0.x)); a0y += XF1(b2f(v0.y));
                a1x += XF0(b2f(v1.x)); a1y += XF1(b2f(v1.y));
                a2x += XF0(b2f(v2.x)); a2y += XF1(b2f(v2.y));
                a3x += XF0(b2f(v3.x)); a3y += XF1(b2f(v3.y));
            }
            for (; i < i1; ++i) {
                int s = eid[i];
                if (H.perm) s = H.perm[s];
                ushort2 v = *(const ushort2*)&h[(size_t)s * DD + lane * 2];
                a0x += XF0(b2f(v.x)); a0y += XF1(b2f(v.y));
            }
        } else {
            const float* h = (const float*)H.base;
            for (; i + 4 <= i1; i += 4) {
                int s0 = eid[i], s1 = eid[i + 1], s2 = eid[i + 2], s3 = eid[i + 3];
                if (H.perm) { s0 = H.perm[s0]; s1 = H.perm[s1]; s2 = H.perm[s2]; s3 = H.perm[s3]; }
                float2 v0 = *(const float2*)&h[(size_t)s0 * DD + lane * 2];
                float2 v1 = *(const float2*)&h[(size_t)s1 * DD + lane * 2];
                float2 v2 = *(const float2*)&h[(size_t)s2 * DD + lane * 2];
                float2 v3 = *(const float2*)&h[(size_t)s3 * DD + lane * 2];
                a0x += XF0(v0.x); a0y += XF1(v0.y);
                a1x += XF0(v1.x); a1y += XF1(v1.y);
                a2x += XF0(v2.x); a2y += XF1(v2.y);
                a3x += XF0(v3.x); a3y += XF1(v3.y);
            }
            for (; i < i1; ++i) {
                int s = eid[i];
                if (H.perm) s = H.perm[s];
                float2 v = *(const float2*)&h[(size_t)s * DD + lane * 2];
                a0x += XF0(v.x); a0y += XF1(v.y);
            }
        }
        float rd = 1.0f / fmaxf((float)(i1 - i0), 1.0f);
        ushort2 o;
        o.x = f2bs((a0x + a1x + a2x + a3x) * rd);
        o.y = f2bs((a0y + a1y + a2y + a3y) * rd);
        *(ushort2*)dst2 = o;
    }
#undef XF0
#undef XF1

    if (doStats) { sds[tid] = 0.0f; __syncthreads(); }

    // ---- MFMA: wave-local rows; K=256 ----
    const int m0 = w * 16;
    f32x4 acc[8] = {};
    for (int ks = 0; ks < 8; ++ks) {
        short8 a = *(const short8*)&As[(m0 + (lane & 15)) * ALD + ks * 32 + ((lane >> 4) & 3) * 8];
#pragma unroll
        for (int ct = 0; ct < 8; ++ct) {
            uint4 braw = wfrag[(ct * 8 + ks) * 64 + lane];
            short8 b = *(short8*)&braw;
            acc[ct] = __builtin_amdgcn_mfma_f32_16x16x32_bf16(a, b, acc[ct], 0, 0, 0);
        }
    }

#pragma unroll
    for (int ct = 0; ct < 8; ++ct) {
        int col = ct * 16 + (lane & 15);
        float bv = bias[col];
        float sv = 0.0f, sq = 0.0f;
#pragma unroll
        for (int r = 0; r < 4; ++r) {
            int grow = rb + m0 + ((lane >> 4) & 3) * 4 + r;
            float v = acc[ct][r] + bv;
            if (grow < Nh) {
                H.out[(size_t)grow * DD + col] = f2bs(v);
                sv += v; sq += v * v;
            }
        }
        if (doStats) {
            sv += __shfl_down(sv, 32, 64); sv += __shfl_down(sv, 16, 64);
            sq += __shfl_down(sq, 32, 64); sq += __shfl_down(sq, 16, 64);
            if (lane < 16) {
                atomicAdd(&sds[ct * 16 + lane], sv);
                atomicAdd(&sds[128 + ct * 16 + lane], sq);
            }
        }
    }
    if (doStats) {
        __syncthreads();
        if (tid < 128) {
            H.PS[(blockIdx.x % nbHalf) * 128 + tid] = sds[tid];
            H.PQ[(blockIdx.x % nbHalf) * 128 + tid] = sds[128 + tid];
        }
    }
}

// ---- predictor MFMA GEMM (K=128): optional fused pair-mult staging, relu ----
__global__ __launch_bounds__(256) void pred_gemm(
    const unsigned short* __restrict__ A,            // plain rows (pair mode if ps!=null)
    const unsigned short* __restrict__ PF,
    const int* __restrict__ ps, const int* __restrict__ pd,
    const int* __restrict__ ns, const int* __restrict__ nd, int EPc,
    const uint4* __restrict__ wfrag, const float* __restrict__ bias,
    unsigned short* __restrict__ out, int Mc)
{
    __shared__ unsigned short As[64 * PLD];
    const int tid = threadIdx.x;
    const int rb = blockIdx.x * 64;

    {
        int r = tid >> 2, cs = (tid & 3) * 32;
        int gr = rb + r;
        unsigned short* dst = &As[r * PLD + cs];
        if (gr < Mc) {
            if (ps) {
                int a = (gr < EPc) ? ps[gr] : ns[gr - EPc];
                int b = (gr < EPc) ? pd[gr] : nd[gr - EPc];
                const unsigned short* ra = PF + (size_t)a * DD + cs;
                const unsigned short* rbp = PF + (size_t)b * DD + cs;
#pragma unroll
                for (int i = 0; i < 32; ++i)
                    dst[i] = f2bs(b2f(ra[i]) * b2f(rbp[i]));
            } else {
                const uint4* sv = (const uint4*)(A + (size_t)gr * DD + cs);
                uint4* dv = (uint4*)dst;
#pragma unroll
                for (int i = 0; i < 4; ++i) dv[i] = sv[i];
            }
        } else {
            uint4 z = {0, 0, 0, 0};
            uint4* dv = (uint4*)dst;
#pragma unroll
            for (int i = 0; i < 4; ++i) dv[i] = z;
        }
    }

    const int w = tid >> 6, lane = tid & 63;
    const int m0 = w * 16;
    f32x4 acc[8] = {};
    for (int ks = 0; ks < 4; ++ks) {
        short8 a = *(const short8*)&As[(m0 + (lane & 15)) * PLD + ks * 32 + ((lane >> 4) & 3) * 8];
#pragma unroll
        for (int ct = 0; ct < 8; ++ct) {
            uint4 braw = wfrag[(ct * 4 + ks) * 64 + lane];
            short8 b = *(short8*)&braw;
            acc[ct] = __builtin_amdgcn_mfma_f32_16x16x32_bf16(a, b, acc[ct], 0, 0, 0);
        }
    }

#pragma unroll
    for (int ct = 0; ct < 8; ++ct) {
        int col = ct * 16 + (lane & 15);
        float bv = bias[col];
#pragma unroll
        for (int r = 0; r < 4; ++r) {
            int grow = rb + m0 + ((lane >> 4) & 3) * 4 + r;
            if (grow >= Mc) continue;
            float v = fmaxf(acc[ct][r] + bv, 0.0f);
            out[(size_t)grow * DD + col] = f2bs(v);
        }
    }
}

// ---- PARALLEL partial reduce -> BN scale/shift. grid = 256: tensor = bid>>7, col = bid&127 ----
__global__ __launch_bounds__(256) void p2bn_fast(
    const float* __restrict__ PSa, const float* __restrict__ PQa,
    float* __restrict__ sca, float* __restrict__ sha,
    const float* __restrict__ PSb, const float* __restrict__ PQb,
    float* __restrict__ scb, float* __restrict__ shb,
    int nb, int M,
    const float* __restrict__ gamma, const float* __restrict__ beta)
{
    int tensor = blockIdx.x >> 7, col = blockIdx.x & 127;
    const float* PS = tensor ? PSb : PSa;
    const float* PQ = tensor ? PQb : PQa;
    float* sc = tensor ? scb : sca;
    float* sh = tensor ? shb : sha;
    __shared__ float sS[256], sQ[256];
    int t = threadIdx.x;
    float s = 0.0f, q = 0.0f;
    for (int b = t; b < nb; b += 256) {
        s += PS[b * 128 + col];
        q += PQ[b * 128 + col];
    }
    sS[t] = s; sQ[t] = q;
    __syncthreads();
    for (int off = 128; off > 0; off >>= 1) {
        if (t < off) { sS[t] += sS[t + off]; sQ[t] += sQ[t + off]; }
        __syncthreads();
    }
    if (t == 0) {
        float m = sS[0] / (float)M;
        float var = fmaxf(sQ[0] / (float)M - m * m, 0.0f);
        float inv = rsqrtf(var + BN_EPS);
        float g = gamma[col];
        sc[col] = g * inv;
        sh[col] = beta[col] - g * m * inv;
    }
}

// ---- PARALLEL column-sum reduce (for summary). grid = 128 ----
__global__ __launch_bounds__(256) void colreduce(const float* __restrict__ PS, int nb,
                                                 float* __restrict__ out) {
    __shared__ float sS[256];
    int col = blockIdx.x;
    int t = threadIdx.x;
    float s = 0.0f;
    for (int b = t; b < nb; b += 256) s += PS[b * 128 + col];
    sS[t] = s;
    __syncthreads();
    for (int off = 128; off > 0; off >>= 1) { if (t < off) sS[t] += sS[t + off]; __syncthreads(); }
    if (t == 0) out[col] = sS[0];
}

// ---- summary -> wsvec ----
__global__ void make_ws(const float* __restrict__ colsum, const float* __restrict__ discW,
                        float* __restrict__ wsv, int M) {
    __shared__ float s[128];
    int t = threadIdx.x;
    s[t] = 1.0f / (1.0f + expf(-(colsum[t] / (float)M)));
    __syncthreads();
    float acc = 0.0f;
#pragma unroll
    for (int j = 0; j < 128; ++j) acc += discW[t * 128 + j] * s[j];
    wsv[t] = acc;
}

// ---- loss stage 1 (bf16 inputs) ----
__global__ __launch_bounds__(256) void loss_partial(
    const unsigned short* __restrict__ P, const unsigned short* __restrict__ Ng,
    const float* __restrict__ wsv, float* __restrict__ lossP, float* __restrict__ lossN, int M)
{
    __shared__ float sP[4], sN[4];
    int lane = threadIdx.x & 63;
    int wave = threadIdx.x >> 6;
    int gw = blockIdx.x * 4 + wave;
    int nw = gridDim.x * 4;
    float w0 = wsv[lane], w1 = wsv[lane + 64];
    float accP = 0.0f, accN = 0.0f;
    for (int row = gw; row < 2 * M; row += nw) {
        const unsigned short* base = (row < M) ? &P[(size_t)row * DD]
                                               : &Ng[(size_t)(row - M) * DD];
        float a = b2f(base[lane]) * w0 + b2f(base[lane + 64]) * w1;
#pragma unroll
        for (int off = 32; off > 0; off >>= 1) a += __shfl_down(a, off, 64);
        if (lane == 0) {
            float x = (row < M) ? -a : a;
            float sp = fmaxf(x, 0.0f) + log1pf(expf(-fabsf(x)));
            if (row < M) accP += sp; else accN += sp;
        }
    }
    if (lane == 0) { sP[wave] = accP; sN[wave] = accN; }
    __syncthreads();
    if (threadIdx.x == 0) {
        lossP[blockIdx.x] = sP[0] + sP[1] + sP[2] + sP[3];
        lossN[blockIdx.x] = sN[0] + sN[1] + sN[2] + sN[3];
    }
}

// ---- loss stage 2 ----
__global__ void write_loss(const float* __restrict__ lossP, const float* __restrict__ lossN,
                           void* __restrict__ outv, int M, const int* __restrict__ flagp) {
    __shared__ float s[256];
    int t = threadIdx.x;
    s[t] = (t < NBLK) ? (lossP[t] + lossN[t]) : 0.0f;
    __syncthreads();
    for (int off = 128; off > 0; off >>= 1) { if (t < off) s[t] += s[t + off]; __syncthreads(); }
    if (t == 0) {
        float v = s[0] / (float)M;
        if (*flagp) ((bf16*)outv)[20000] = __float2bfloat16(v);
        else        ((float*)outv)[20000] = v;
    }
}

// ---- final 128 -> 1 matvec ----
__global__ __launch_bounds__(256) void final_mv(
    const unsigned short* __restrict__ ZB, const float* __restrict__ pW3,
    const float* __restrict__ pb3,
    void* __restrict__ outv, int nRows, const int* __restrict__ flagp) {
    int row = blockIdx.x * 4 + (threadIdx.x >> 6);
    int lane = threadIdx.x & 63;
    if (row >= nRows) return;
    float a = b2f(ZB[(size_t)row * DD + lane]) * pW3[lane]
            + b2f(ZB[(size_t)row * DD + lane + 64]) * pW3[lane + 64];
#pragma unroll
    for (int off = 32; off > 0; off >>= 1) a += __shfl_down(a, off, 64);
    if (lane == 0) {
        float v = a + pb3[0];
        if (*flagp) ((bf16*)outv)[row] = __float2bfloat16(v);
        else        ((float*)outv)[row] = v;
    }
}

extern "C" void kernel_launch(void* const* d_in, const int* in_sizes, int n_in,
                              void* d_out, int out_size, void* d_ws, size_t ws_size,
                              hipStream_t stream)
{
    const void* x      = d_in[0];
    const int* srcA[3] = {(const int*)d_in[1], (const int*)d_in[3], (const int*)d_in[5]};
    const int* dstA[3] = {(const int*)d_in[2], (const int*)d_in[4], (const int*)d_in[6]};
    const int* perm    = (const int*)d_in[7];
    const int* pos_src = (const int*)d_in[8];
    const int* pos_dst = (const int*)d_in[9];
    const int* neg_src = (const int*)d_in[10];
    const int* neg_dst = (const int*)d_in[11];

    const int N1 = 50000, N2 = 25000, N3 = 12500;
    const int E[3] = {750000, 250000, 125000};
    const int EP = 10000;
    const int NCAT = 87500;

    // ---- ws layout (4-byte units), peak 13,206,016 fl = 52.8 MiB ----
    float* wsf = (float*)d_ws;
    int*   wsi = (int*)d_ws;
    int*   flagp = wsi;
    float* lossP = wsf + 64;
    float* lossN = wsf + 224;
    float* wsvec = wsf + 512;
    float* scP0 = wsf + 640;  float* shP0 = wsf + 768;
    float* scN0 = wsf + 896;  float* shN0 = wsf + 1024;
    float* scP1 = wsf + 1152; float* shP1 = wsf + 1280;
    float* scN1 = wsf + 1408; float* shN1 = wsf + 1536;
    int*   bsums = wsi + 1664;
    float* colsum = wsf + 1920;
    float* PSP = wsf + 2048;                      // 100352
    float* PQP = wsf + 102400;
    float* PSN = wsf + 202752;
    float* PQN = wsf + 303104;                    // ends 403456
    int* histAll = wsi + 403456;
    int* curAll  = wsi + 491008;
    int* rpAll   = wsi + 578560;
    int* eidAll  = wsi + 666112;                  // ends 1,791,112
    const size_t WfB = 1791232;
    float* WS[3] = {wsf + WfB, wsf + WfB + 32896, wsf + WfB + 65792};
    float* WN[3] = {wsf + WfB + 16384, wsf + WfB + 49280, wsf + WfB + 82176};
    float* BV[3] = {wsf + WfB + 32768, wsf + WfB + 65664, wsf + WfB + 98560};
    float* G0  = wsf + WfB + 98688;  float* BE0 = wsf + WfB + 98816;
    float* G1  = wsf + WfB + 98944;  float* BE1 = wsf + WfB + 99072;
    float* DW  = wsf + WfB + 99200;
    float* PW1 = wsf + WfB + 115584; float* PB1 = wsf + WfB + 131968;
    float* PW2 = wsf + WfB + 132096; float* PB2 = wsf + WfB + 148480;
    float* PW3 = wsf + WfB + 148608; float* PB3 = wsf + WfB + 148736;
    unsigned short* wfragL[3] = {(unsigned short*)(wsf + 1940480),
                                 (unsigned short*)(wsf + 1956864),
                                 (unsigned short*)(wsf + 1973248)};
    unsigned short* wfragP[2] = {(unsigned short*)(wsf + 1989632),
                                 (unsigned short*)(wsf + 1997824)};
    unsigned short* PF  = (unsigned short*)(wsf + 2006016);
    unsigned short* NF  = (unsigned short*)(wsf + 2806016);
    unsigned short* H2P = (unsigned short*)(wsf + 3606016);
    unsigned short* H2N = (unsigned short*)(wsf + 5206016);
    unsigned short* H1P = (unsigned short*)(wsf + 6806016);
    unsigned short* H1N = (unsigned short*)(wsf + 10006016);  // ends 13,206,016
    // predictor overlays (H1 dead by then):
    unsigned short* ZA = H1N;
    unsigned short* ZB = H1N + (size_t)2560000;

    // ---- dtype detect + weight conversion ----
    detect_dtype<<<1, 256, 0, stream>>>((const unsigned int*)x, flagp);
    CvtTable tab;
    const int widx[20] = {12,13,14, 15,16,17, 18,19,20, 21,22,23,24, 25, 26,27, 28,29, 30,31};
    float* wdst[20] = {WS[0],WN[0],BV[0], WS[1],WN[1],BV[1], WS[2],WN[2],BV[2],
                       G0,BE0,G1,BE1, DW, PW1,PB1, PW2,PB2, PW3,PB3};
    const int wn[20] = {16384,16384,128, 16384,16384,128, 16384,16384,128,
                        128,128,128,128, 16384, 16384,128, 16384,128, 128,1};
    int tot = 0;
    for (int k = 0; k < 20; ++k) {
        tab.src[k] = d_in[widx[k]];
        tab.off[k] = (int)(wdst[k] - wsf);
        tab.n[k] = wn[k];
        tot += wn[k];
    }
    tab.total = tot;
    cvt_all<<<(tot + 255) / 256, 256, 0, stream>>>(tab, wsf, flagp);

    // ---- CSR build ----
    hipMemsetAsync(histAll, 0, (size_t)(2 * NCAT + 128) * 4, stream);
    hist_win<<<512, 256, 0, stream>>>(dstA[0], E[0], dstA[1], E[1], dstA[2], E[2], histAll);
    {
        int nb = (NCAT / 4 + 255) / 256;
        scan_bsum<<<nb, 256, 0, stream>>>(histAll, NCAT, bsums);
        scan_bscan<<<1, 256, 0, stream>>>(bsums, nb, rpAll + NCAT);
        scan_apply<<<nb, 256, 0, stream>>>(histAll, NCAT, bsums, rpAll);
    }
    csr_fill_win<<<512, 256, 0, stream>>>(
        srcA[0], dstA[0], E[0], srcA[1], dstA[1], E[1], srcA[2], dstA[2], E[2],
        rpAll, curAll, eidAll);

    // ---- MFMA W-fragment tables ----
    WfAll wa;
    wa.W1[0] = WS[0]; wa.W2[0] = WN[0]; wa.dst[0] = wfragL[0]; wa.KS[0] = 8; wa.start[0] = 0;
    wa.W1[1] = WS[1]; wa.W2[1] = WN[1]; wa.dst[1] = wfragL[1]; wa.KS[1] = 8; wa.start[1] = 4096;
    wa.W1[2] = WS[2]; wa.W2[2] = WN[2]; wa.dst[2] = wfragL[2]; wa.KS[2] = 8; wa.start[2] = 8192;
    wa.W1[3] = PW1;   wa.W2[3] = nullptr; wa.dst[3] = wfragP[0]; wa.KS[3] = 4; wa.start[3] = 12288;
    wa.W1[4] = PW2;   wa.W2[4] = nullptr; wa.dst[4] = wfragP[1]; wa.KS[4] = 4; wa.start[4] = 14336;
    wa.total = 16384;
    wfrag_all<<<64, 256, 0, stream>>>(wa);

    const int nb0 = (N1 + 63) / 64, nb1 = (N2 + 63) / 64, nb2 = (N3 + 63) / 64;

    // ===== layer 0: fused gather+gemm, both halves in one dispatch =====
    {
        HalfArgs hP = {x, nullptr, nullptr, nullptr, H1P, PSP, PQP};
        HalfArgs hN = {x, perm,    nullptr, nullptr, H1N, PSN, PQN};
        sage_layer<<<2 * nb0, 256, 0, stream>>>(hP, hN, flagp, rpAll, eidAll,
                                                (const uint4*)wfragL[0], BV[0], N1, nb0);
    }
    p2bn_fast<<<256, 256, 0, stream>>>(PSP, PQP, scP0, shP0, PSN, PQN, scN0, shN0, nb0, N1, G0, BE0);

    // ===== layer 1 =====
    {
        HalfArgs hP = {H1P, nullptr, scP0, shP0, H2P, PSP, PQP};
        HalfArgs hN = {H1N, nullptr, scN0, shN0, H2N, PSN, PQN};
        sage_layer<<<2 * nb1, 256, 0, stream>>>(hP, hN, nullptr, rpAll + 50000, eidAll,
                                                (const uint4*)wfragL[1], BV[1], N2, nb1);
    }
    p2bn_fast<<<256, 256, 0, stream>>>(PSP, PQP, scP1, shP1, PSN, PQN, scN1, shN1, nb1, N2, G1, BE1);

    // ===== layer 2 (stats only for P -> summary) =====
    {
        HalfArgs hP = {H2P, nullptr, scP1, shP1, PF, PSP, PQP};
        HalfArgs hN = {H2N, nullptr, scN1, shN1, NF, nullptr, nullptr};
        sage_layer<<<2 * nb2, 256, 0, stream>>>(hP, hN, nullptr, rpAll + 75000, eidAll,
                                                (const uint4*)wfragL[2], BV[2], N3, nb2);
    }
    colreduce<<<128, 256, 0, stream>>>(PSP, nb2, colsum);
    make_ws<<<1, 128, 0, stream>>>(colsum, DW, wsvec, N3);

    // ===== discriminator loss =====
    loss_partial<<<NBLK, 256, 0, stream>>>(PF, NF, wsvec, lossP, lossN, N3);
    write_loss<<<1, 256, 0, stream>>>(lossP, lossN, d_out, N3, flagp);

    // ===== predictor MLP: pair-mult fused into gemm1 =====
    pred_gemm<<<(2 * EP + 63) / 64, 256, 0, stream>>>(
        nullptr, PF, pos_src, pos_dst, neg_src, neg_dst, EP,
        (const uint4*)wfragP[0], PB1, ZA, 2 * EP);
    pred_gemm<<<(2 * EP + 63) / 64, 256, 0, stream>>>(
        ZA, nullptr, nullptr, nullptr, nullptr, nullptr, 0,
        (const uint4*)wfragP[1], PB2, ZB, 2 * EP);
    final_mv<<<(2 * EP + 3) / 4, 256, 0, stream>>>(ZB, PW3, PB3, d_out, 2 * EP, flagp);
}

// Round 15
// 664.643 us; speedup vs baseline: 1.2210x; 1.2210x over previous
//
#include <hip/hip_runtime.h>
#include <hip/hip_bf16.h>

#define DD 128
#define BN_EPS 1e-5f
#define NBLK 160   // blocks for loss partial kernel
#define ALD 264    // LDS row stride (bf16) for K=256
#define PLD 136    // LDS row stride (bf16) for K=128

typedef __hip_bfloat16 bf16;
typedef __attribute__((ext_vector_type(8))) short short8;
typedef __attribute__((ext_vector_type(4))) float f32x4;

__device__ __forceinline__ float b2f(unsigned short u) {
    union { float f; unsigned int i; } x; x.i = ((unsigned int)u) << 16; return x.f;
}
__device__ __forceinline__ unsigned short f2bs(float v) {
    bf16 h = __float2bfloat16(v);
    return *(unsigned short*)&h;
}

// ---- dtype detect: flag=1 if d_in[0] is packed bf16, 0 if f32 ----
__global__ void detect_dtype(const unsigned int* __restrict__ x, int* __restrict__ flag) {
    __shared__ int s[256];
    int t = threadIdx.x;
    unsigned int u = x[t];
    unsigned int e = (u >> 7) & 0xFFu;
    s[t] = ((e >= 90u && e <= 140u) || ((u & 0xFFFFu) == 0u)) ? 1 : 0;
    __syncthreads();
    for (int off = 128; off > 0; off >>= 1) { if (t < off) s[t] += s[t + off]; __syncthreads(); }
    if (t == 0) *flag = (s[0] >= 128) ? 1 : 0;
}

// ---- fused weight conversion ----
struct CvtTable {
    const void* src[20];
    int off[20];
    int n[20];
    int total;
};
__global__ __launch_bounds__(256) void cvt_all(CvtTable tab, float* __restrict__ wsf,
                                               const int* __restrict__ flagp) {
    int i = blockIdx.x * 256 + threadIdx.x;
    if (i >= tab.total) return;
    int k = 0;
    while (i >= tab.n[k]) { i -= tab.n[k]; ++k; }
    float v;
    if (*flagp) v = b2f(((const unsigned short*)tab.src[k])[i]);
    else        v = ((const float*)tab.src[k])[i];
    wsf[tab.off[k] + i] = v;
}

// ---- fused MFMA B-fragment builder (5 tables) ----
struct WfAll {
    const float* W1[5];
    const float* W2[5];
    unsigned short* dst[5];
    int KS[5];
    int start[5];
    int total;
};
__global__ __launch_bounds__(256) void wfrag_all(WfAll w) {
    int t = blockIdx.x * 256 + threadIdx.x;
    if (t >= w.total) return;
    int k = 0;
    while (k < 4 && t >= w.start[k + 1]) ++k;
    int lt = t - w.start[k];
    int KS = w.KS[k];
    int lane = lt & 63;
    int ks = (lt >> 6) % KS;
    int ct = lt / (KS * 64);
    int n = ct * 16 + (lane & 15);
    unsigned short v[8];
#pragma unroll
    for (int j = 0; j < 8; ++j) {
        int kk = ks * 32 + ((lane >> 4) & 3) * 8 + j;
        float wv = (kk < 128) ? w.W1[k][kk * DD + n] : w.W2[k][(kk - 128) * DD + n];
        v[j] = f2bs(wv);
    }
    *(uint4*)&w.dst[k][(size_t)lt * 8] = *(uint4*)v;
}

// ---- CSR: windowed histogram over concatenated dst space ----
__global__ __launch_bounds__(256) void hist_win(
    const int* __restrict__ d0, int e0, const int* __restrict__ d1, int e1,
    const int* __restrict__ d2, int e2, int* __restrict__ hist) {
    int stride = gridDim.x * 256;
    int t0 = blockIdx.x * 256 + threadIdx.x;
    for (int w = 0; w < 4; ++w) {
        int dlo = w * 12500, dhi = dlo + 12500;
        for (int e = t0; e < e0; e += stride) {
            int d = d0[e];
            if (d >= dlo && d < dhi) atomicAdd(&hist[d], 1);
        }
    }
    for (int e = t0; e < e1; e += stride) atomicAdd(&hist[50000 + d1[e]], 1);
    for (int e = t0; e < e2; e += stride) atomicAdd(&hist[75000 + d2[e]], 1);
}

// ---- hierarchical exclusive scan ----
__global__ __launch_bounds__(256) void scan_bsum(const int* __restrict__ cnt, int n,
                                                 int* __restrict__ bsums) {
    __shared__ int sm[256];
    int t = threadIdx.x, b = blockIdx.x;
    int i4 = b * 256 + t;
    int local = 0;
    if (i4 * 4 < n) { int4 v = ((const int4*)cnt)[i4]; local = v.x + v.y + v.z + v.w; }
    sm[t] = local;
    __syncthreads();
    for (int off = 128; off > 0; off >>= 1) { if (t < off) sm[t] += sm[t + off]; __syncthreads(); }
    if (t == 0) bsums[b] = sm[0];
}
__global__ void scan_bscan(int* __restrict__ bsums, int nb, int* __restrict__ rowptr_n) {
    __shared__ int wsum[4];
    int t = threadIdx.x, lane = t & 63, w = t >> 6;
    int v = (t < nb) ? bsums[t] : 0;
    int inc = v;
    for (int off = 1; off < 64; off <<= 1) {
        int u = __shfl_up(inc, off, 64);
        if (lane >= off) inc += u;
    }
    if (lane == 63) wsum[w] = inc;
    __syncthreads();
    int wo = 0;
    for (int i = 0; i < w; ++i) wo += wsum[i];
    if (t < nb) bsums[t] = wo + inc - v;
    if (t == 255) *rowptr_n = wo + inc;
}
__global__ __launch_bounds__(256) void scan_apply(const int* __restrict__ cnt, int n,
                                                  const int* __restrict__ bsums,
                                                  int* __restrict__ rowptr) {
    __shared__ int wsum[4];
    int t = threadIdx.x, b = blockIdx.x, lane = t & 63, w = t >> 6;
    int i4 = b * 256 + t;
    int4 v = {0, 0, 0, 0};
    bool valid = (i4 * 4 < n);
    if (valid) v = ((const int4*)cnt)[i4];
    int local = v.x + v.y + v.z + v.w;
    int inc = local;
    for (int off = 1; off < 64; off <<= 1) {
        int u = __shfl_up(inc, off, 64);
        if (lane >= off) inc += u;
    }
    if (lane == 63) wsum[w] = inc;
    __syncthreads();
    int wo = 0;
    for (int i = 0; i < w; ++i) wo += wsum[i];
    if (valid) {
        int acc = bsums[b] + wo + inc - local;
        int base = i4 * 4;
        rowptr[base + 0] = acc; acc += v.x;
        rowptr[base + 1] = acc; acc += v.y;
        rowptr[base + 2] = acc; acc += v.z;
        rowptr[base + 3] = acc;
    }
}

// ---- CSR fill, windowed by dst range ----
__global__ __launch_bounds__(256) void csr_fill_win(
    const int* __restrict__ s0, const int* __restrict__ d0, int e0,
    const int* __restrict__ s1, const int* __restrict__ d1, int e1,
    const int* __restrict__ s2, const int* __restrict__ d2, int e2,
    const int* __restrict__ rpAll, int* __restrict__ cur, int* __restrict__ eid) {
    int stride = gridDim.x * 256;
    int t0 = blockIdx.x * 256 + threadIdx.x;
    for (int w = 0; w < 4; ++w) {
        int dlo = w * 12500, dhi = dlo + 12500;
        for (int e = t0; e < e0; e += stride) {
            int d = d0[e];
            if (d >= dlo && d < dhi)
                eid[rpAll[d] + atomicAdd(&cur[d], 1)] = s0[e];
        }
    }
    for (int e = t0; e < e1; e += stride) {
        int gd = 50000 + d1[e];
        eid[rpAll[gd] + atomicAdd(&cur[gd], 1)] = s1[e];
    }
    for (int e = t0; e < e2; e += stride) {
        int gd = 75000 + d2[e];
        eid[rpAll[gd] + atomicAdd(&cur[gd], 1)] = s2[e];
    }
}

// ---- CSR gather (two-half batched): one WAVE per dst row, 8-deep unroll ----
__global__ __launch_bounds__(256) void gather2(
    const void* __restrict__ hvP, const void* __restrict__ hvN,
    const int* __restrict__ flagp,
    const int* __restrict__ permP, const int* __restrict__ permN,
    const float* __restrict__ scP, const float* __restrict__ shP,
    const float* __restrict__ scN, const float* __restrict__ shN,
    const int* __restrict__ rowptr, const int* __restrict__ eid,
    int N, int nRows, unsigned short* __restrict__ out)
{
    int row = blockIdx.x * 4 + (threadIdx.x >> 6);
    int lane = threadIdx.x & 63;
    if (row >= nRows) return;
    int half = row >= N;
    int d = half ? row - N : row;
    const void* hv = half ? hvN : hvP;
    const int* perm = half ? permN : permP;
    const float* sc = half ? scN : scP;
    const float* sh = half ? shN : shP;
    int i0 = rowptr[d], i1 = rowptr[d + 1];
    int abf = flagp ? *flagp : 1;
    bool bn = (sc != nullptr);
    float c0 = 1.0f, c1 = 1.0f, h0 = 0.0f, h1 = 0.0f;
    if (bn) { c0 = sc[lane * 2]; c1 = sc[lane * 2 + 1]; h0 = sh[lane * 2]; h1 = sh[lane * 2 + 1]; }

#define XF0(v) (bn ? fmaxf(c0 * (v) + h0, 0.0f) : (v))
#define XF1(v) (bn ? fmaxf(c1 * (v) + h1, 0.0f) : (v))
    float ax[8] = {}, ay[8] = {};
    int i = i0;
    if (abf) {
        const unsigned short* h = (const unsigned short*)hv;
        for (; i + 8 <= i1; i += 8) {
            int sI[8];
#pragma unroll
            for (int j = 0; j < 8; ++j) sI[j] = eid[i + j];
            if (perm) {
#pragma unroll
                for (int j = 0; j < 8; ++j) sI[j] = perm[sI[j]];
            }
            ushort2 v[8];
#pragma unroll
            for (int j = 0; j < 8; ++j) v[j] = *(const ushort2*)&h[(size_t)sI[j] * DD + lane * 2];
#pragma unroll
            for (int j = 0; j < 8; ++j) { ax[j] += XF0(b2f(v[j].x)); ay[j] += XF1(b2f(v[j].y)); }
        }
        for (; i < i1; ++i) {
            int s = eid[i];
            if (perm) s = perm[s];
            ushort2 v = *(const ushort2*)&h[(size_t)s * DD + lane * 2];
            ax[0] += XF0(b2f(v.x)); ay[0] += XF1(b2f(v.y));
        }
    } else {
        const float* h = (const float*)hv;
        for (; i + 8 <= i1; i += 8) {
            int sI[8];
#pragma unroll
            for (int j = 0; j < 8; ++j) sI[j] = eid[i + j];
            if (perm) {
#pragma unroll
                for (int j = 0; j < 8; ++j) sI[j] = perm[sI[j]];
            }
            float2 v[8];
#pragma unroll
            for (int j = 0; j < 8; ++j) v[j] = *(const float2*)&h[(size_t)sI[j] * DD + lane * 2];
#pragma unroll
            for (int j = 0; j < 8; ++j) { ax[j] += XF0(v[j].x); ay[j] += XF1(v[j].y); }
        }
        for (; i < i1; ++i) {
            int s = eid[i];
            if (perm) s = perm[s];
            float2 v = *(const float2*)&h[(size_t)s * DD + lane * 2];
            ax[0] += XF0(v.x); ay[0] += XF1(v.y);
        }
    }
#undef XF0
#undef XF1
    float sx = (ax[0] + ax[1]) + (ax[2] + ax[3]) + (ax[4] + ax[5]) + (ax[6] + ax[7]);
    float sy = (ay[0] + ay[1]) + (ay[2] + ay[3]) + (ay[4] + ay[5]) + (ay[6] + ay[7]);
    float rd = 1.0f / fmaxf((float)(i1 - i0), 1.0f);
    ushort2 o;
    o.x = f2bs(sx * rd);
    o.y = f2bs(sy * rd);
    *(ushort2*)&out[(size_t)row * DD + lane * 2] = o;
}

// ---- two-half MFMA GEMM (K=256): grid = (1 or 2) * nbHalf blocks of 64 rows ----
struct GHalf {
    const void* A1;          // self rows
    const int* gather;       // optional row remap
    const float* sc;         // optional BN fold
    const float* sh;
    const unsigned short* A2;  // gathered mean rows (bf16)
    unsigned short* out;
    float* PS;               // optional per-block column stats
    float* PQ;
};
__global__ __launch_bounds__(256) void mfma_gemm2(
    GHalf hP, GHalf hN, const int* __restrict__ flagp,
    const uint4* __restrict__ wfrag, const float* __restrict__ bias,
    int Nh, int nbHalf)
{
    __shared__ unsigned short As[64 * ALD];
    __shared__ float sds[256];
    const int tid = threadIdx.x;
    const int half = blockIdx.x / nbHalf;
    const int rb = (blockIdx.x % nbHalf) * 64;
    const GHalf H = half ? hN : hP;
    const int abf = flagp ? *flagp : 1;
    const bool bn = (H.sc != nullptr);
    const bool doStats = (H.PS != nullptr);

    {
        int r = tid >> 2, cs = (tid & 3) * 32;
        int gr = rb + r;
        unsigned short* dst = &As[r * ALD + cs];
        if (gr < Nh) {
            int ar = H.gather ? H.gather[gr] : gr;
            if (abf) {
                const unsigned short* s = (const unsigned short*)H.A1 + (size_t)ar * DD + cs;
                if (bn) {
#pragma unroll
                    for (int i = 0; i < 32; ++i) {
                        float v = b2f(s[i]);
                        v = fmaxf(H.sc[cs + i] * v + H.sh[cs + i], 0.0f);
                        dst[i] = f2bs(v);
                    }
                } else {
                    const uint4* sv = (const uint4*)s;
                    uint4* dv = (uint4*)dst;
#pragma unroll
                    for (int i = 0; i < 4; ++i) dv[i] = sv[i];
                }
            } else {
                const float* s = (const float*)H.A1 + (size_t)ar * DD + cs;
#pragma unroll
                for (int i = 0; i < 32; ++i) dst[i] = f2bs(s[i]);
            }
            const uint4* s2 = (const uint4*)(H.A2 + (size_t)gr * DD + cs);
            uint4* d2 = (uint4*)(dst + 128);
#pragma unroll
            for (int i = 0; i < 4; ++i) d2[i] = s2[i];
        } else {
            uint4 z = {0, 0, 0, 0};
            uint4* dv = (uint4*)dst;
#pragma unroll
            for (int i = 0; i < 4; ++i) dv[i] = z;
            uint4* d2 = (uint4*)(dst + 128);
#pragma unroll
            for (int i = 0; i < 4; ++i) d2[i] = z;
        }
    }
    if (doStats) { sds[tid] = 0.0f; }
    __syncthreads();

    const int w = tid >> 6, lane = tid & 63;
    const int m0 = w * 16;
    f32x4 acc[8] = {};
    for (int ks = 0; ks < 8; ++ks) {
        short8 a = *(const short8*)&As[(m0 + (lane & 15)) * ALD + ks * 32 + ((lane >> 4) & 3) * 8];
#pragma unroll
        for (int ct = 0; ct < 8; ++ct) {
            uint4 braw = wfrag[(ct * 8 + ks) * 64 + lane];
            short8 b = *(short8*)&braw;
            acc[ct] = __builtin_amdgcn_mfma_f32_16x16x32_bf16(a, b, acc[ct], 0, 0, 0);
        }
    }

#pragma unroll
    for (int ct = 0; ct < 8; ++ct) {
        int col = ct * 16 + (lane & 15);
        float bv = bias[col];
        float sv = 0.0f, sq = 0.0f;
#pragma unroll
        for (int r = 0; r < 4; ++r) {
            int grow = rb + m0 + ((lane >> 4) & 3) * 4 + r;
            float v = acc[ct][r] + bv;
            if (grow < Nh) {
                H.out[(size_t)grow * DD + col] = f2bs(v);
                sv += v; sq += v * v;
            }
        }
        if (doStats) {
            sv += __shfl_down(sv, 32, 64); sv += __shfl_down(sv, 16, 64);
            sq += __shfl_down(sq, 32, 64); sq += __shfl_down(sq, 16, 64);
            if (lane < 16) {
                atomicAdd(&sds[ct * 16 + lane], sv);
                atomicAdd(&sds[128 + ct * 16 + lane], sq);
            }
        }
    }
    if (doStats) {
        __syncthreads();
        if (tid < 128) {
            H.PS[(blockIdx.x % nbHalf) * 128 + tid] = sds[tid];
            H.PQ[(blockIdx.x % nbHalf) * 128 + tid] = sds[128 + tid];
        }
    }
}

// ---- predictor MFMA GEMM (K=128): optional fused pair-mult staging, relu ----
__global__ __launch_bounds__(256) void pred_gemm(
    const unsigned short* __restrict__ A,
    const unsigned short* __restrict__ PF,
    const int* __restrict__ ps, const int* __restrict__ pd,
    const int* __restrict__ ns, const int* __restrict__ nd, int EPc,
    const uint4* __restrict__ wfrag, const float* __restrict__ bias,
    unsigned short* __restrict__ out, int Mc)
{
    __shared__ unsigned short As[64 * PLD];
    const int tid = threadIdx.x;
    const int rb = blockIdx.x * 64;

    {
        int r = tid >> 2, cs = (tid & 3) * 32;
        int gr = rb + r;
        unsigned short* dst = &As[r * PLD + cs];
        if (gr < Mc) {
            if (ps) {
                int a = (gr < EPc) ? ps[gr] : ns[gr - EPc];
                int b = (gr < EPc) ? pd[gr] : nd[gr - EPc];
                const unsigned short* ra = PF + (size_t)a * DD + cs;
                const unsigned short* rbp = PF + (size_t)b * DD + cs;
#pragma unroll
                for (int i = 0; i < 32; ++i)
                    dst[i] = f2bs(b2f(ra[i]) * b2f(rbp[i]));
            } else {
                const uint4* sv = (const uint4*)(A + (size_t)gr * DD + cs);
                uint4* dv = (uint4*)dst;
#pragma unroll
                for (int i = 0; i < 4; ++i) dv[i] = sv[i];
            }
        } else {
            uint4 z = {0, 0, 0, 0};
            uint4* dv = (uint4*)dst;
#pragma unroll
            for (int i = 0; i < 4; ++i) dv[i] = z;
        }
    }
    __syncthreads();

    const int w = tid >> 6, lane = tid & 63;
    const int m0 = w * 16;
    f32x4 acc[8] = {};
    for (int ks = 0; ks < 4; ++ks) {
        short8 a = *(const short8*)&As[(m0 + (lane & 15)) * PLD + ks * 32 + ((lane >> 4) & 3) * 8];
#pragma unroll
        for (int ct = 0; ct < 8; ++ct) {
            uint4 braw = wfrag[(ct * 4 + ks) * 64 + lane];
            short8 b = *(short8*)&braw;
            acc[ct] = __builtin_amdgcn_mfma_f32_16x16x32_bf16(a, b, acc[ct], 0, 0, 0);
        }
    }

#pragma unroll
    for (int ct = 0; ct < 8; ++ct) {
        int col = ct * 16 + (lane & 15);
        float bv = bias[col];
#pragma unroll
        for (int r = 0; r < 4; ++r) {
            int grow = rb + m0 + ((lane >> 4) & 3) * 4 + r;
            if (grow >= Mc) continue;
            float v = fmaxf(acc[ct][r] + bv, 0.0f);
            out[(size_t)grow * DD + col] = f2bs(v);
        }
    }
}

// ---- PARALLEL partial reduce -> BN scale/shift. grid = 256 ----
__global__ __launch_bounds__(256) void p2bn_fast(
    const float* __restrict__ PSa, const float* __restrict__ PQa,
    float* __restrict__ sca, float* __restrict__ sha,
    const float* __restrict__ PSb, const float* __restrict__ PQb,
    float* __restrict__ scb, float* __restrict__ shb,
    int nb, int M,
    const float* __restrict__ gamma, const float* __restrict__ beta)
{
    int tensor = blockIdx.x >> 7, col = blockIdx.x & 127;
    const float* PS = tensor ? PSb : PSa;
    const float* PQ = tensor ? PQb : PQa;
    float* sc = tensor ? scb : sca;
    float* sh = tensor ? shb : sha;
    __shared__ float sS[256], sQ[256];
    int t = threadIdx.x;
    float s = 0.0f, q = 0.0f;
    for (int b = t; b < nb; b += 256) {
        s += PS[b * 128 + col];
        q += PQ[b * 128 + col];
    }
    sS[t] = s; sQ[t] = q;
    __syncthreads();
    for (int off = 128; off > 0; off >>= 1) {
        if (t < off) { sS[t] += sS[t + off]; sQ[t] += sQ[t + off]; }
        __syncthreads();
    }
    if (t == 0) {
        float m = sS[0] / (float)M;
        float var = fmaxf(sQ[0] / (float)M - m * m, 0.0f);
        float inv = rsqrtf(var + BN_EPS);
        float g = gamma[col];
        sc[col] = g * inv;
        sh[col] = beta[col] - g * m * inv;
    }
}

// ---- PARALLEL column-sum reduce. grid = 128 ----
__global__ __launch_bounds__(256) void colreduce(const float* __restrict__ PS, int nb,
                                                 float* __restrict__ out) {
    __shared__ float sS[256];
    int col = blockIdx.x;
    int t = threadIdx.x;
    float s = 0.0f;
    for (int b = t; b < nb; b += 256) s += PS[b * 128 + col];
    sS[t] = s;
    __syncthreads();
    for (int off = 128; off > 0; off >>= 1) { if (t < off) sS[t] += sS[t + off]; __syncthreads(); }
    if (t == 0) out[col] = sS[0];
}

// ---- summary -> wsvec ----
__global__ void make_ws(const float* __restrict__ colsum, const float* __restrict__ discW,
                        float* __restrict__ wsv, int M) {
    __shared__ float s[128];
    int t = threadIdx.x;
    s[t] = 1.0f / (1.0f + expf(-(colsum[t] / (float)M)));
    __syncthreads();
    float acc = 0.0f;
#pragma unroll
    for (int j = 0; j < 128; ++j) acc += discW[t * 128 + j] * s[j];
    wsv[t] = acc;
}

// ---- loss stage 1 (bf16 inputs) ----
__global__ __launch_bounds__(256) void loss_partial(
    const unsigned short* __restrict__ P, const unsigned short* __restrict__ Ng,
    const float* __restrict__ wsv, float* __restrict__ lossP, float* __restrict__ lossN, int M)
{
    __shared__ float sP[4], sN[4];
    int lane = threadIdx.x & 63;
    int wave = threadIdx.x >> 6;
    int gw = blockIdx.x * 4 + wave;
    int nw = gridDim.x * 4;
    float w0 = wsv[lane], w1 = wsv[lane + 64];
    float accP = 0.0f, accN = 0.0f;
    for (int row = gw; row < 2 * M; row += nw) {
        const unsigned short* base = (row < M) ? &P[(size_t)row * DD]
                                               : &Ng[(size_t)(row - M) * DD];
        float a = b2f(base[lane]) * w0 + b2f(base[lane + 64]) * w1;
#pragma unroll
        for (int off = 32; off > 0; off >>= 1) a += __shfl_down(a, off, 64);
        if (lane == 0) {
            float x = (row < M) ? -a : a;
            float sp = fmaxf(x, 0.0f) + log1pf(expf(-fabsf(x)));
            if (row < M) accP += sp; else accN += sp;
        }
    }
    if (lane == 0) { sP[wave] = accP; sN[wave] = accN; }
    __syncthreads();
    if (threadIdx.x == 0) {
        lossP[blockIdx.x] = sP[0] + sP[1] + sP[2] + sP[3];
        lossN[blockIdx.x] = sN[0] + sN[1] + sN[2] + sN[3];
    }
}

// ---- loss stage 2 ----
__global__ void write_loss(const float* __restrict__ lossP, const float* __restrict__ lossN,
                           void* __restrict__ outv, int M, const int* __restrict__ flagp) {
    __shared__ float s[256];
    int t = threadIdx.x;
    s[t] = (t < NBLK) ? (lossP[t] + lossN[t]) : 0.0f;
    __syncthreads();
    for (int off = 128; off > 0; off >>= 1) { if (t < off) s[t] += s[t + off]; __syncthreads(); }
    if (t == 0) {
        float v = s[0] / (float)M;
        if (*flagp) ((bf16*)outv)[20000] = __float2bfloat16(v);
        else        ((float*)outv)[20000] = v;
    }
}

// ---- final 128 -> 1 matvec ----
__global__ __launch_bounds__(256) void final_mv(
    const unsigned short* __restrict__ ZB, const float* __restrict__ pW3,
    const float* __restrict__ pb3,
    void* __restrict__ outv, int nRows, const int* __restrict__ flagp) {
    int row = blockIdx.x * 4 + (threadIdx.x >> 6);
    int lane = threadIdx.x & 63;
    if (row >= nRows) return;
    float a = b2f(ZB[(size_t)row * DD + lane]) * pW3[lane]
            + b2f(ZB[(size_t)row * DD + lane + 64]) * pW3[lane + 64];
#pragma unroll
    for (int off = 32; off > 0; off >>= 1) a += __shfl_down(a, off, 64);
    if (lane == 0) {
        float v = a + pb3[0];
        if (*flagp) ((bf16*)outv)[row] = __float2bfloat16(v);
        else        ((float*)outv)[row] = v;
    }
}

extern "C" void kernel_launch(void* const* d_in, const int* in_sizes, int n_in,
                              void* d_out, int out_size, void* d_ws, size_t ws_size,
                              hipStream_t stream)
{
    const void* x      = d_in[0];
    const int* srcA[3] = {(const int*)d_in[1], (const int*)d_in[3], (const int*)d_in[5]};
    const int* dstA[3] = {(const int*)d_in[2], (const int*)d_in[4], (const int*)d_in[6]};
    const int* perm    = (const int*)d_in[7];
    const int* pos_src = (const int*)d_in[8];
    const int* pos_dst = (const int*)d_in[9];
    const int* neg_src = (const int*)d_in[10];
    const int* neg_dst = (const int*)d_in[11];

    const int N1 = 50000, N2 = 25000, N3 = 12500;
    const int E[3] = {750000, 250000, 125000};
    const int EP = 10000;
    const int NCAT = 87500;

    // ---- ws layout (4-byte units), peak 16,406,016 fl = 65.6 MiB (round-13 proven) ----
    float* wsf = (float*)d_ws;
    int*   wsi = (int*)d_ws;
    int*   flagp = wsi;
    float* lossP = wsf + 64;
    float* lossN = wsf + 224;
    float* wsvec = wsf + 512;
    float* scP0 = wsf + 640;  float* shP0 = wsf + 768;
    float* scN0 = wsf + 896;  float* shN0 = wsf + 1024;
    float* scP1 = wsf + 1152; float* shP1 = wsf + 1280;
    float* scN1 = wsf + 1408; float* shN1 = wsf + 1536;
    int*   bsums = wsi + 1664;
    float* colsum = wsf + 1920;
    float* PSP = wsf + 2048;
    float* PQP = wsf + 102400;
    float* PSN = wsf + 202752;
    float* PQN = wsf + 303104;
    int* histAll = wsi + 403456;
    int* curAll  = wsi + 491008;
    int* rpAll   = wsi + 578560;
    int* eidAll  = wsi + 666112;
    const size_t WfB = 1791232;
    float* WS[3] = {wsf + WfB, wsf + WfB + 32896, wsf + WfB + 65792};
    float* WN[3] = {wsf + WfB + 16384, wsf + WfB + 49280, wsf + WfB + 82176};
    float* BV[3] = {wsf + WfB + 32768, wsf + WfB + 65664, wsf + WfB + 98560};
    float* G0  = wsf + WfB + 98688;  float* BE0 = wsf + WfB + 98816;
    float* G1  = wsf + WfB + 98944;  float* BE1 = wsf + WfB + 99072;
    float* DW  = wsf + WfB + 99200;
    float* PW1 = wsf + WfB + 115584; float* PB1 = wsf + WfB + 131968;
    float* PW2 = wsf + WfB + 132096; float* PB2 = wsf + WfB + 148480;
    float* PW3 = wsf + WfB + 148608; float* PB3 = wsf + WfB + 148736;
    unsigned short* wfragL[3] = {(unsigned short*)(wsf + 1940480),
                                 (unsigned short*)(wsf + 1956864),
                                 (unsigned short*)(wsf + 1973248)};
    unsigned short* wfragP[2] = {(unsigned short*)(wsf + 1989632),
                                 (unsigned short*)(wsf + 1997824)};
    unsigned short* PF  = (unsigned short*)(wsf + 2006016);
    unsigned short* NF  = (unsigned short*)(wsf + 2806016);
    unsigned short* H2P = (unsigned short*)(wsf + 3606016);
    unsigned short* H2N = (unsigned short*)(wsf + 5206016);
    unsigned short* H1P = (unsigned short*)(wsf + 6806016);
    unsigned short* H1N = (unsigned short*)(wsf + 10006016);
    unsigned short* AGG = (unsigned short*)(wsf + 13206016);  // 50000 rows bf16 (3.2M fl)
    unsigned short* ZA = H1N;
    unsigned short* ZB = H1N + (size_t)2560000;

    // ---- dtype detect + weight conversion ----
    detect_dtype<<<1, 256, 0, stream>>>((const unsigned int*)x, flagp);
    CvtTable tab;
    const int widx[20] = {12,13,14, 15,16,17, 18,19,20, 21,22,23,24, 25, 26,27, 28,29, 30,31};
    float* wdst[20] = {WS[0],WN[0],BV[0], WS[1],WN[1],BV[1], WS[2],WN[2],BV[2],
                       G0,BE0,G1,BE1, DW, PW1,PB1, PW2,PB2, PW3,PB3};
    const int wn[20] = {16384,16384,128, 16384,16384,128, 16384,16384,128,
                        128,128,128,128, 16384, 16384,128, 16384,128, 128,1};
    int tot = 0;
    for (int k = 0; k < 20; ++k) {
        tab.src[k] = d_in[widx[k]];
        tab.off[k] = (int)(wdst[k] - wsf);
        tab.n[k] = wn[k];
        tot += wn[k];
    }
    tab.total = tot;
    cvt_all<<<(tot + 255) / 256, 256, 0, stream>>>(tab, wsf, flagp);

    // ---- CSR build ----
    hipMemsetAsync(histAll, 0, (size_t)(2 * NCAT + 128) * 4, stream);
    hist_win<<<512, 256, 0, stream>>>(dstA[0], E[0], dstA[1], E[1], dstA[2], E[2], histAll);
    {
        int nb = (NCAT / 4 + 255) / 256;
        scan_bsum<<<nb, 256, 0, stream>>>(histAll, NCAT, bsums);
        scan_bscan<<<1, 256, 0, stream>>>(bsums, nb, rpAll + NCAT);
        scan_apply<<<nb, 256, 0, stream>>>(histAll, NCAT, bsums, rpAll);
    }
    csr_fill_win<<<512, 256, 0, stream>>>(
        srcA[0], dstA[0], E[0], srcA[1], dstA[1], E[1], srcA[2], dstA[2], E[2],
        rpAll, curAll, eidAll);

    // ---- MFMA W-fragment tables ----
    WfAll wa;
    wa.W1[0] = WS[0]; wa.W2[0] = WN[0]; wa.dst[0] = wfragL[0]; wa.KS[0] = 8; wa.start[0] = 0;
    wa.W1[1] = WS[1]; wa.W2[1] = WN[1]; wa.dst[1] = wfragL[1]; wa.KS[1] = 8; wa.start[1] = 4096;
    wa.W1[2] = WS[2]; wa.W2[2] = WN[2]; wa.dst[2] = wfragL[2]; wa.KS[2] = 8; wa.start[2] = 8192;
    wa.W1[3] = PW1;   wa.W2[3] = nullptr; wa.dst[3] = wfragP[0]; wa.KS[3] = 4; wa.start[3] = 12288;
    wa.W1[4] = PW2;   wa.W2[4] = nullptr; wa.dst[4] = wfragP[1]; wa.KS[4] = 4; wa.start[4] = 14336;
    wa.total = 16384;
    wfrag_all<<<64, 256, 0, stream>>>(wa);

    const int nb0 = (N1 + 63) / 64, nb1 = (N2 + 63) / 64, nb2 = (N3 + 63) / 64;

    // ===== layer 0: per-half gather+gemm (AGG holds one half at a time) =====
    gather2<<<(N1 + 3) / 4, 256, 0, stream>>>(
        x, x, flagp, nullptr, nullptr, nullptr, nullptr, nullptr, nullptr,
        rpAll, eidAll, N1, N1, AGG);
    {
        GHalf hP = {x, nullptr, nullptr, nullptr, AGG, H1P, PSP, PQP};
        mfma_gemm2<<<nb0, 256, 0, stream>>>(hP, hP, flagp, (const uint4*)wfragL[0], BV[0], N1, nb0);
    }
    gather2<<<(N1 + 3) / 4, 256, 0, stream>>>(
        x, x, flagp, perm, perm, nullptr, nullptr, nullptr, nullptr,
        rpAll, eidAll, N1, N1, AGG);
    {
        GHalf hN = {x, perm, nullptr, nullptr, AGG, H1N, PSN, PQN};
        mfma_gemm2<<<nb0, 256, 0, stream>>>(hN, hN, flagp, (const uint4*)wfragL[0], BV[0], N1, nb0);
    }
    p2bn_fast<<<256, 256, 0, stream>>>(PSP, PQP, scP0, shP0, PSN, PQN, scN0, shN0, nb0, N1, G0, BE0);

    // ===== layer 1: batched gather (BN fold), one two-half gemm =====
    gather2<<<(2 * N2 + 3) / 4, 256, 0, stream>>>(
        H1P, H1N, nullptr, nullptr, nullptr, scP0, shP0, scN0, shN0,
        rpAll + 50000, eidAll, N2, 2 * N2, AGG);
    {
        GHalf hP = {H1P, nullptr, scP0, shP0, AGG,                      H2P, PSP, PQP};
        GHalf hN = {H1N, nullptr, scN0, shN0, AGG + (size_t)N2 * DD,    H2N, PSN, PQN};
        mfma_gemm2<<<2 * nb1, 256, 0, stream>>>(hP, hN, nullptr, (const uint4*)wfragL[1], BV[1], N2, nb1);
    }
    p2bn_fast<<<256, 256, 0, stream>>>(PSP, PQP, scP1, shP1, PSN, PQN, scN1, shN1, nb1, N2, G1, BE1);

    // ===== layer 2: batched gather (BN fold), one two-half gemm (P stats only) =====
    gather2<<<(2 * N3 + 3) / 4, 256, 0, stream>>>(
        H2P, H2N, nullptr, nullptr, nullptr, scP1, shP1, scN1, shN1,
        rpAll + 75000, eidAll, N3, 2 * N3, AGG);
    {
        GHalf hP = {H2P, nullptr, scP1, shP1, AGG,                      PF, PSP, PQP};
        GHalf hN = {H2N, nullptr, scN1, shN1, AGG + (size_t)N3 * DD,    NF, nullptr, nullptr};
        mfma_gemm2<<<2 * nb2, 256, 0, stream>>>(hP, hN, nullptr, (const uint4*)wfragL[2], BV[2], N3, nb2);
    }
    colreduce<<<128, 256, 0, stream>>>(PSP, nb2, colsum);
    make_ws<<<1, 128, 0, stream>>>(colsum, DW, wsvec, N3);

    // ===== discriminator loss =====
    loss_partial<<<NBLK, 256, 0, stream>>>(PF, NF, wsvec, lossP, lossN, N3);
    write_loss<<<1, 256, 0, stream>>>(lossP, lossN, d_out, N3, flagp);

    // ===== predictor MLP: pair-mult fused into gemm1 =====
    pred_gemm<<<(2 * EP + 63) / 64, 256, 0, stream>>>(
        nullptr, PF, pos_src, pos_dst, neg_src, neg_dst, EP,
        (const uint4*)wfragP[0], PB1, ZA, 2 * EP);
    pred_gemm<<<(2 * EP + 63) / 64, 256, 0, stream>>>(
        ZA, nullptr, nullptr, nullptr, nullptr, nullptr, 0,
        (const uint4*)wfragP[1], PB2, ZB, 2 * EP);
    final_mv<<<(2 * EP + 3) / 4, 256, 0, stream>>>(ZB, PW3, PB3, d_out, 2 * EP, flagp);
}

// Round 16
// 628.585 us; speedup vs baseline: 1.2910x; 1.0574x over previous
//
#include <hip/hip_runtime.h>
#include <hip/hip_bf16.h>

#define DD 128
#define BN_EPS 1e-5f
#define NBLK 160   // blocks for loss partial kernel
#define ALD 264    // LDS row stride (bf16) for K=256
#define PLD 136    // LDS row stride (bf16) for K=128

typedef __hip_bfloat16 bf16;
typedef __attribute__((ext_vector_type(8))) short short8;
typedef __attribute__((ext_vector_type(4))) float f32x4;

__device__ __forceinline__ float b2f(unsigned short u) {
    union { float f; unsigned int i; } x; x.i = ((unsigned int)u) << 16; return x.f;
}
__device__ __forceinline__ unsigned short f2bs(float v) {
    bf16 h = __float2bfloat16(v);
    return *(unsigned short*)&h;
}

// ---- dtype detect: flag=1 if d_in[0] is packed bf16, 0 if f32 ----
__global__ void detect_dtype(const unsigned int* __restrict__ x, int* __restrict__ flag) {
    __shared__ int s[256];
    int t = threadIdx.x;
    unsigned int u = x[t];
    unsigned int e = (u >> 7) & 0xFFu;
    s[t] = ((e >= 90u && e <= 140u) || ((u & 0xFFFFu) == 0u)) ? 1 : 0;
    __syncthreads();
    for (int off = 128; off > 0; off >>= 1) { if (t < off) s[t] += s[t + off]; __syncthreads(); }
    if (t == 0) *flag = (s[0] >= 128) ? 1 : 0;
}

// ---- fused weight conversion ----
struct CvtTable {
    const void* src[20];
    int off[20];
    int n[20];
    int total;
};
__global__ __launch_bounds__(256) void cvt_all(CvtTable tab, float* __restrict__ wsf,
                                               const int* __restrict__ flagp) {
    int i = blockIdx.x * 256 + threadIdx.x;
    if (i >= tab.total) return;
    int k = 0;
    while (i >= tab.n[k]) { i -= tab.n[k]; ++k; }
    float v;
    if (*flagp) v = b2f(((const unsigned short*)tab.src[k])[i]);
    else        v = ((const float*)tab.src[k])[i];
    wsf[tab.off[k] + i] = v;
}

// ---- fused MFMA B-fragment builder (5 tables) ----
struct WfAll {
    const float* W1[5];
    const float* W2[5];
    unsigned short* dst[5];
    int KS[5];
    int start[5];
    int total;
};
__global__ __launch_bounds__(256) void wfrag_all(WfAll w) {
    int t = blockIdx.x * 256 + threadIdx.x;
    if (t >= w.total) return;
    int k = 0;
    while (k < 4 && t >= w.start[k + 1]) ++k;
    int lt = t - w.start[k];
    int KS = w.KS[k];
    int lane = lt & 63;
    int ks = (lt >> 6) % KS;
    int ct = lt / (KS * 64);
    int n = ct * 16 + (lane & 15);
    unsigned short v[8];
#pragma unroll
    for (int j = 0; j < 8; ++j) {
        int kk = ks * 32 + ((lane >> 4) & 3) * 8 + j;
        float wv = (kk < 128) ? w.W1[k][kk * DD + n] : w.W2[k][(kk - 128) * DD + n];
        v[j] = f2bs(wv);
    }
    *(uint4*)&w.dst[k][(size_t)lt * 8] = *(uint4*)v;
}

// ---- CSR: single-pass histogram over concatenated dst space (hist fits L2) ----
__global__ __launch_bounds__(256) void hist_all(
    const int* __restrict__ d0, int e0, const int* __restrict__ d1, int e1,
    const int* __restrict__ d2, int e2, int* __restrict__ hist) {
    int e = blockIdx.x * 256 + threadIdx.x;
    if (e < e0) atomicAdd(&hist[d0[e]], 1);
    else if (e < e0 + e1) atomicAdd(&hist[50000 + d1[e - e0]], 1);
    else if (e < e0 + e1 + e2) atomicAdd(&hist[75000 + d2[e - e0 - e1]], 1);
}

// ---- hierarchical exclusive scan ----
__global__ __launch_bounds__(256) void scan_bsum(const int* __restrict__ cnt, int n,
                                                 int* __restrict__ bsums) {
    __shared__ int sm[256];
    int t = threadIdx.x, b = blockIdx.x;
    int i4 = b * 256 + t;
    int local = 0;
    if (i4 * 4 < n) { int4 v = ((const int4*)cnt)[i4]; local = v.x + v.y + v.z + v.w; }
    sm[t] = local;
    __syncthreads();
    for (int off = 128; off > 0; off >>= 1) { if (t < off) sm[t] += sm[t + off]; __syncthreads(); }
    if (t == 0) bsums[b] = sm[0];
}
__global__ void scan_bscan(int* __restrict__ bsums, int nb, int* __restrict__ rowptr_n) {
    __shared__ int wsum[4];
    int t = threadIdx.x, lane = t & 63, w = t >> 6;
    int v = (t < nb) ? bsums[t] : 0;
    int inc = v;
    for (int off = 1; off < 64; off <<= 1) {
        int u = __shfl_up(inc, off, 64);
        if (lane >= off) inc += u;
    }
    if (lane == 63) wsum[w] = inc;
    __syncthreads();
    int wo = 0;
    for (int i = 0; i < w; ++i) wo += wsum[i];
    if (t < nb) bsums[t] = wo + inc - v;
    if (t == 255) *rowptr_n = wo + inc;
}
__global__ __launch_bounds__(256) void scan_apply(const int* __restrict__ cnt, int n,
                                                  const int* __restrict__ bsums,
                                                  int* __restrict__ rowptr) {
    __shared__ int wsum[4];
    int t = threadIdx.x, b = blockIdx.x, lane = t & 63, w = t >> 6;
    int i4 = b * 256 + t;
    int4 v = {0, 0, 0, 0};
    bool valid = (i4 * 4 < n);
    if (valid) v = ((const int4*)cnt)[i4];
    int local = v.x + v.y + v.z + v.w;
    int inc = local;
    for (int off = 1; off < 64; off <<= 1) {
        int u = __shfl_up(inc, off, 64);
        if (lane >= off) inc += u;
    }
    if (lane == 63) wsum[w] = inc;
    __syncthreads();
    int wo = 0;
    for (int i = 0; i < w; ++i) wo += wsum[i];
    if (valid) {
        int acc = bsums[b] + wo + inc - local;
        int base = i4 * 4;
        rowptr[base + 0] = acc; acc += v.x;
        rowptr[base + 1] = acc; acc += v.y;
        rowptr[base + 2] = acc; acc += v.z;
        rowptr[base + 3] = acc;
    }
}

// ---- CSR fill, windowed by dst range (proven 4-window form) ----
__global__ __launch_bounds__(256) void csr_fill_win(
    const int* __restrict__ s0, const int* __restrict__ d0, int e0,
    const int* __restrict__ s1, const int* __restrict__ d1, int e1,
    const int* __restrict__ s2, const int* __restrict__ d2, int e2,
    const int* __restrict__ rpAll, int* __restrict__ cur, int* __restrict__ eid) {
    int stride = gridDim.x * 256;
    int t0 = blockIdx.x * 256 + threadIdx.x;
    for (int w = 0; w < 4; ++w) {
        int dlo = w * 12500, dhi = dlo + 12500;
        for (int e = t0; e < e0; e += stride) {
            int d = d0[e];
            if (d >= dlo && d < dhi)
                eid[rpAll[d] + atomicAdd(&cur[d], 1)] = s0[e];
        }
    }
    for (int e = t0; e < e1; e += stride) {
        int gd = 50000 + d1[e];
        eid[rpAll[gd] + atomicAdd(&cur[gd], 1)] = s1[e];
    }
    for (int e = t0; e < e2; e += stride) {
        int gd = 75000 + d2[e];
        eid[rpAll[gd] + atomicAdd(&cur[gd], 1)] = s2[e];
    }
}

// ---- CSR gather (two-half batched): one WAVE per dst row, 4-deep unroll ----
__global__ __launch_bounds__(256) void gather2(
    const void* __restrict__ hvP, const void* __restrict__ hvN,
    const int* __restrict__ flagp,
    const int* __restrict__ permP, const int* __restrict__ permN,
    const float* __restrict__ scP, const float* __restrict__ shP,
    const float* __restrict__ scN, const float* __restrict__ shN,
    const int* __restrict__ rowptr, const int* __restrict__ eid,
    int N, int nRows, unsigned short* __restrict__ out)
{
    int row = blockIdx.x * 4 + (threadIdx.x >> 6);
    int lane = threadIdx.x & 63;
    if (row >= nRows) return;
    int half = row >= N;
    int d = half ? row - N : row;
    const void* hv = half ? hvN : hvP;
    const int* perm = half ? permN : permP;
    const float* sc = half ? scN : scP;
    const float* sh = half ? shN : shP;
    int i0 = rowptr[d], i1 = rowptr[d + 1];
    int abf = flagp ? *flagp : 1;
    bool bn = (sc != nullptr);
    float c0 = 1.0f, c1 = 1.0f, h0 = 0.0f, h1 = 0.0f;
    if (bn) { c0 = sc[lane * 2]; c1 = sc[lane * 2 + 1]; h0 = sh[lane * 2]; h1 = sh[lane * 2 + 1]; }

#define XF0(v) (bn ? fmaxf(c0 * (v) + h0, 0.0f) : (v))
#define XF1(v) (bn ? fmaxf(c1 * (v) + h1, 0.0f) : (v))
    float a0x = 0, a0y = 0, a1x = 0, a1y = 0, a2x = 0, a2y = 0, a3x = 0, a3y = 0;
    int i = i0;
    if (abf) {
        const unsigned short* h = (const unsigned short*)hv;
        for (; i + 4 <= i1; i += 4) {
            int s0 = eid[i], s1 = eid[i + 1], s2 = eid[i + 2], s3 = eid[i + 3];
            if (perm) { s0 = perm[s0]; s1 = perm[s1]; s2 = perm[s2]; s3 = perm[s3]; }
            ushort2 v0 = *(const ushort2*)&h[(size_t)s0 * DD + lane * 2];
            ushort2 v1 = *(const ushort2*)&h[(size_t)s1 * DD + lane * 2];
            ushort2 v2 = *(const ushort2*)&h[(size_t)s2 * DD + lane * 2];
            ushort2 v3 = *(const ushort2*)&h[(size_t)s3 * DD + lane * 2];
            a0x += XF0(b2f(v0.x)); a0y += XF1(b2f(v0.y));
            a1x += XF0(b2f(v1.x)); a1y += XF1(b2f(v1.y));
            a2x += XF0(b2f(v2.x)); a2y += XF1(b2f(v2.y));
            a3x += XF0(b2f(v3.x)); a3y += XF1(b2f(v3.y));
        }
        for (; i < i1; ++i) {
            int s = eid[i];
            if (perm) s = perm[s];
            ushort2 v = *(const ushort2*)&h[(size_t)s * DD + lane * 2];
            a0x += XF0(b2f(v.x)); a0y += XF1(b2f(v.y));
        }
    } else {
        const float* h = (const float*)hv;
        for (; i + 4 <= i1; i += 4) {
            int s0 = eid[i], s1 = eid[i + 1], s2 = eid[i + 2], s3 = eid[i + 3];
            if (perm) { s0 = perm[s0]; s1 = perm[s1]; s2 = perm[s2]; s3 = perm[s3]; }
            float2 v0 = *(const float2*)&h[(size_t)s0 * DD + lane * 2];
            float2 v1 = *(const float2*)&h[(size_t)s1 * DD + lane * 2];
            float2 v2 = *(const float2*)&h[(size_t)s2 * DD + lane * 2];
            float2 v3 = *(const float2*)&h[(size_t)s3 * DD + lane * 2];
            a0x += XF0(v0.x); a0y += XF1(v0.y);
            a1x += XF0(v1.x); a1y += XF1(v1.y);
            a2x += XF0(v2.x); a2y += XF1(v2.y);
            a3x += XF0(v3.x); a3y += XF1(v3.y);
        }
        for (; i < i1; ++i) {
            int s = eid[i];
            if (perm) s = perm[s];
            float2 v = *(const float2*)&h[(size_t)s * DD + lane * 2];
            a0x += XF0(v.x); a0y += XF1(v.y);
        }
    }
#undef XF0
#undef XF1
    float rd = 1.0f / fmaxf((float)(i1 - i0), 1.0f);
    ushort2 o;
    o.x = f2bs((a0x + a1x + a2x + a3x) * rd);
    o.y = f2bs((a0y + a1y + a2y + a3y) * rd);
    *(ushort2*)&out[(size_t)row * DD + lane * 2] = o;
}

// ---- two-half MFMA GEMM (K=256): grid = (1 or 2) * nbHalf blocks of 64 rows ----
struct GHalf {
    const void* A1;
    const int* gather;
    const float* sc;
    const float* sh;
    const unsigned short* A2;
    unsigned short* out;
    float* PS;
    float* PQ;
};
__global__ __launch_bounds__(256) void mfma_gemm2(
    GHalf hP, GHalf hN, const int* __restrict__ flagp,
    const uint4* __restrict__ wfrag, const float* __restrict__ bias,
    int Nh, int nbHalf)
{
    __shared__ unsigned short As[64 * ALD];
    __shared__ float sds[256];
    const int tid = threadIdx.x;
    const int half = blockIdx.x / nbHalf;
    const int rb = (blockIdx.x % nbHalf) * 64;
    const GHalf H = half ? hN : hP;
    const int abf = flagp ? *flagp : 1;
    const bool bn = (H.sc != nullptr);
    const bool doStats = (H.PS != nullptr);

    {
        int r = tid >> 2, cs = (tid & 3) * 32;
        int gr = rb + r;
        unsigned short* dst = &As[r * ALD + cs];
        if (gr < Nh) {
            int ar = H.gather ? H.gather[gr] : gr;
            if (abf) {
                const unsigned short* s = (const unsigned short*)H.A1 + (size_t)ar * DD + cs;
                if (bn) {
#pragma unroll
                    for (int i = 0; i < 32; ++i) {
                        float v = b2f(s[i]);
                        v = fmaxf(H.sc[cs + i] * v + H.sh[cs + i], 0.0f);
                        dst[i] = f2bs(v);
                    }
                } else {
                    const uint4* sv = (const uint4*)s;
                    uint4* dv = (uint4*)dst;
#pragma unroll
                    for (int i = 0; i < 4; ++i) dv[i] = sv[i];
                }
            } else {
                const float* s = (const float*)H.A1 + (size_t)ar * DD + cs;
#pragma unroll
                for (int i = 0; i < 32; ++i) dst[i] = f2bs(s[i]);
            }
            const uint4* s2 = (const uint4*)(H.A2 + (size_t)gr * DD + cs);
            uint4* d2 = (uint4*)(dst + 128);
#pragma unroll
            for (int i = 0; i < 4; ++i) d2[i] = s2[i];
        } else {
            uint4 z = {0, 0, 0, 0};
            uint4* dv = (uint4*)dst;
#pragma unroll
            for (int i = 0; i < 4; ++i) dv[i] = z;
            uint4* d2 = (uint4*)(dst + 128);
#pragma unroll
            for (int i = 0; i < 4; ++i) d2[i] = z;
        }
    }
    if (doStats) { sds[tid] = 0.0f; }
    __syncthreads();

    const int w = tid >> 6, lane = tid & 63;
    const int m0 = w * 16;
    f32x4 acc[8] = {};
    for (int ks = 0; ks < 8; ++ks) {
        short8 a = *(const short8*)&As[(m0 + (lane & 15)) * ALD + ks * 32 + ((lane >> 4) & 3) * 8];
#pragma unroll
        for (int ct = 0; ct < 8; ++ct) {
            uint4 braw = wfrag[(ct * 8 + ks) * 64 + lane];
            short8 b = *(short8*)&braw;
            acc[ct] = __builtin_amdgcn_mfma_f32_16x16x32_bf16(a, b, acc[ct], 0, 0, 0);
        }
    }

#pragma unroll
    for (int ct = 0; ct < 8; ++ct) {
        int col = ct * 16 + (lane & 15);
        float bv = bias[col];
        float sv = 0.0f, sq = 0.0f;
#pragma unroll
        for (int r = 0; r < 4; ++r) {
            int grow = rb + m0 + ((lane >> 4) & 3) * 4 + r;
            float v = acc[ct][r] + bv;
            if (grow < Nh) {
                H.out[(size_t)grow * DD + col] = f2bs(v);
                sv += v; sq += v * v;
            }
        }
        if (doStats) {
            sv += __shfl_down(sv, 32, 64); sv += __shfl_down(sv, 16, 64);
            sq += __shfl_down(sq, 32, 64); sq += __shfl_down(sq, 16, 64);
            if (lane < 16) {
                atomicAdd(&sds[ct * 16 + lane], sv);
                atomicAdd(&sds[128 + ct * 16 + lane], sq);
            }
        }
    }
    if (doStats) {
        __syncthreads();
        if (tid < 128) {
            H.PS[(blockIdx.x % nbHalf) * 128 + tid] = sds[tid];
            H.PQ[(blockIdx.x % nbHalf) * 128 + tid] = sds[128 + tid];
        }
    }
}

// ---- predictor MFMA GEMM (K=128): optional fused pair-mult staging, relu ----
__global__ __launch_bounds__(256) void pred_gemm(
    const unsigned short* __restrict__ A,
    const unsigned short* __restrict__ PF,
    const int* __restrict__ ps, const int* __restrict__ pd,
    const int* __restrict__ ns, const int* __restrict__ nd, int EPc,
    const uint4* __restrict__ wfrag, const float* __restrict__ bias,
    unsigned short* __restrict__ out, int Mc)
{
    __shared__ unsigned short As[64 * PLD];
    const int tid = threadIdx.x;
    const int rb = blockIdx.x * 64;

    {
        int r = tid >> 2, cs = (tid & 3) * 32;
        int gr = rb + r;
        unsigned short* dst = &As[r * PLD + cs];
        if (gr < Mc) {
            if (ps) {
                int a = (gr < EPc) ? ps[gr] : ns[gr - EPc];
                int b = (gr < EPc) ? pd[gr] : nd[gr - EPc];
                const unsigned short* ra = PF + (size_t)a * DD + cs;
                const unsigned short* rbp = PF + (size_t)b * DD + cs;
#pragma unroll
                for (int i = 0; i < 32; ++i)
                    dst[i] = f2bs(b2f(ra[i]) * b2f(rbp[i]));
            } else {
                const uint4* sv = (const uint4*)(A + (size_t)gr * DD + cs);
                uint4* dv = (uint4*)dst;
#pragma unroll
                for (int i = 0; i < 4; ++i) dv[i] = sv[i];
            }
        } else {
            uint4 z = {0, 0, 0, 0};
            uint4* dv = (uint4*)dst;
#pragma unroll
            for (int i = 0; i < 4; ++i) dv[i] = z;
        }
    }
    __syncthreads();

    const int w = tid >> 6, lane = tid & 63;
    const int m0 = w * 16;
    f32x4 acc[8] = {};
    for (int ks = 0; ks < 4; ++ks) {
        short8 a = *(const short8*)&As[(m0 + (lane & 15)) * PLD + ks * 32 + ((lane >> 4) & 3) * 8];
#pragma unroll
        for (int ct = 0; ct < 8; ++ct) {
            uint4 braw = wfrag[(ct * 4 + ks) * 64 + lane];
            short8 b = *(short8*)&braw;
            acc[ct] = __builtin_amdgcn_mfma_f32_16x16x32_bf16(a, b, acc[ct], 0, 0, 0);
        }
    }

#pragma unroll
    for (int ct = 0; ct < 8; ++ct) {
        int col = ct * 16 + (lane & 15);
        float bv = bias[col];
#pragma unroll
        for (int r = 0; r < 4; ++r) {
            int grow = rb + m0 + ((lane >> 4) & 3) * 4 + r;
            if (grow >= Mc) continue;
            float v = fmaxf(acc[ct][r] + bv, 0.0f);
            out[(size_t)grow * DD + col] = f2bs(v);
        }
    }
}

// ---- PARALLEL partial reduce -> BN scale/shift. grid = 256 ----
__global__ __launch_bounds__(256) void p2bn_fast(
    const float* __restrict__ PSa, const float* __restrict__ PQa,
    float* __restrict__ sca, float* __restrict__ sha,
    const float* __restrict__ PSb, const float* __restrict__ PQb,
    float* __restrict__ scb, float* __restrict__ shb,
    int nb, int M,
    const float* __restrict__ gamma, const float* __restrict__ beta)
{
    int tensor = blockIdx.x >> 7, col = blockIdx.x & 127;
    const float* PS = tensor ? PSb : PSa;
    const float* PQ = tensor ? PQb : PQa;
    float* sc = tensor ? scb : sca;
    float* sh = tensor ? shb : sha;
    __shared__ float sS[256], sQ[256];
    int t = threadIdx.x;
    float s = 0.0f, q = 0.0f;
    for (int b = t; b < nb; b += 256) {
        s += PS[b * 128 + col];
        q += PQ[b * 128 + col];
    }
    sS[t] = s; sQ[t] = q;
    __syncthreads();
    for (int off = 128; off > 0; off >>= 1) {
        if (t < off) { sS[t] += sS[t + off]; sQ[t] += sQ[t + off]; }
        __syncthreads();
    }
    if (t == 0) {
        float m = sS[0] / (float)M;
        float var = fmaxf(sQ[0] / (float)M - m * m, 0.0f);
        float inv = rsqrtf(var + BN_EPS);
        float g = gamma[col];
        sc[col] = g * inv;
        sh[col] = beta[col] - g * m * inv;
    }
}

// ---- PARALLEL column-sum reduce. grid = 128 ----
__global__ __launch_bounds__(256) void colreduce(const float* __restrict__ PS, int nb,
                                                 float* __restrict__ out) {
    __shared__ float sS[256];
    int col = blockIdx.x;
    int t = threadIdx.x;
    float s = 0.0f;
    for (int b = t; b < nb; b += 256) s += PS[b * 128 + col];
    sS[t] = s;
    __syncthreads();
    for (int off = 128; off > 0; off >>= 1) { if (t < off) sS[t] += sS[t + off]; __syncthreads(); }
    if (t == 0) out[col] = sS[0];
}

// ---- summary -> wsvec ----
__global__ void make_ws(const float* __restrict__ colsum, const float* __restrict__ discW,
                        float* __restrict__ wsv, int M) {
    __shared__ float s[128];
    int t = threadIdx.x;
    s[t] = 1.0f / (1.0f + expf(-(colsum[t] / (float)M)));
    __syncthreads();
    float acc = 0.0f;
#pragma unroll
    for (int j = 0; j < 128; ++j) acc += discW[t * 128 + j] * s[j];
    wsv[t] = acc;
}

// ---- loss stage 1 (bf16 inputs) ----
__global__ __launch_bounds__(256) void loss_partial(
    const unsigned short* __restrict__ P, const unsigned short* __restrict__ Ng,
    const float* __restrict__ wsv, float* __restrict__ lossP, float* __restrict__ lossN, int M)
{
    __shared__ float sP[4], sN[4];
    int lane = threadIdx.x & 63;
    int wave = threadIdx.x >> 6;
    int gw = blockIdx.x * 4 + wave;
    int nw = gridDim.x * 4;
    float w0 = wsv[lane], w1 = wsv[lane + 64];
    float accP = 0.0f, accN = 0.0f;
    for (int row = gw; row < 2 * M; row += nw) {
        const unsigned short* base = (row < M) ? &P[(size_t)row * DD]
                                               : &Ng[(size_t)(row - M) * DD];
        float a = b2f(base[lane]) * w0 + b2f(base[lane + 64]) * w1;
#pragma unroll
        for (int off = 32; off > 0; off >>= 1) a += __shfl_down(a, off, 64);
        if (lane == 0) {
            float x = (row < M) ? -a : a;
            float sp = fmaxf(x, 0.0f) + log1pf(expf(-fabsf(x)));
            if (row < M) accP += sp; else accN += sp;
        }
    }
    if (lane == 0) { sP[wave] = accP; sN[wave] = accN; }
    __syncthreads();
    if (threadIdx.x == 0) {
        lossP[blockIdx.x] = sP[0] + sP[1] + sP[2] + sP[3];
        lossN[blockIdx.x] = sN[0] + sN[1] + sN[2] + sN[3];
    }
}

// ---- loss stage 2 ----
__global__ void write_loss(const float* __restrict__ lossP, const float* __restrict__ lossN,
                           void* __restrict__ outv, int M, const int* __restrict__ flagp) {
    __shared__ float s[256];
    int t = threadIdx.x;
    s[t] = (t < NBLK) ? (lossP[t] + lossN[t]) : 0.0f;
    __syncthreads();
    for (int off = 128; off > 0; off >>= 1) { if (t < off) s[t] += s[t + off]; __syncthreads(); }
    if (t == 0) {
        float v = s[0] / (float)M;
        if (*flagp) ((bf16*)outv)[20000] = __float2bfloat16(v);
        else        ((float*)outv)[20000] = v;
    }
}

// ---- final 128 -> 1 matvec ----
__global__ __launch_bounds__(256) void final_mv(
    const unsigned short* __restrict__ ZB, const float* __restrict__ pW3,
    const float* __restrict__ pb3,
    void* __restrict__ outv, int nRows, const int* __restrict__ flagp) {
    int row = blockIdx.x * 4 + (threadIdx.x >> 6);
    int lane = threadIdx.x & 63;
    if (row >= nRows) return;
    float a = b2f(ZB[(size_t)row * DD + lane]) * pW3[lane]
            + b2f(ZB[(size_t)row * DD + lane + 64]) * pW3[lane + 64];
#pragma unroll
    for (int off = 32; off > 0; off >>= 1) a += __shfl_down(a, off, 64);
    if (lane == 0) {
        float v = a + pb3[0];
        if (*flagp) ((bf16*)outv)[row] = __float2bfloat16(v);
        else        ((float*)outv)[row] = v;
    }
}

extern "C" void kernel_launch(void* const* d_in, const int* in_sizes, int n_in,
                              void* d_out, int out_size, void* d_ws, size_t ws_size,
                              hipStream_t stream)
{
    const void* x      = d_in[0];
    const int* srcA[3] = {(const int*)d_in[1], (const int*)d_in[3], (const int*)d_in[5]};
    const int* dstA[3] = {(const int*)d_in[2], (const int*)d_in[4], (const int*)d_in[6]};
    const int* perm    = (const int*)d_in[7];
    const int* pos_src = (const int*)d_in[8];
    const int* pos_dst = (const int*)d_in[9];
    const int* neg_src = (const int*)d_in[10];
    const int* neg_dst = (const int*)d_in[11];

    const int N1 = 50000, N2 = 25000, N3 = 12500;
    const int E[3] = {750000, 250000, 125000};
    const int EP = 10000;
    const int NCAT = 87500;

    // ---- ws layout (4-byte units). Base peak 65.6 MiB; big-WS path 78.4 MiB ----
    float* wsf = (float*)d_ws;
    int*   wsi = (int*)d_ws;
    int*   flagp = wsi;
    float* lossP = wsf + 64;
    float* lossN = wsf + 224;
    float* wsvec = wsf + 512;
    float* scP0 = wsf + 640;  float* shP0 = wsf + 768;
    float* scN0 = wsf + 896;  float* shN0 = wsf + 1024;
    float* scP1 = wsf + 1152; float* shP1 = wsf + 1280;
    float* scN1 = wsf + 1408; float* shN1 = wsf + 1536;
    int*   bsums = wsi + 1664;
    float* colsum = wsf + 1920;
    float* PSP = wsf + 2048;
    float* PQP = wsf + 102400;
    float* PSN = wsf + 202752;
    float* PQN = wsf + 303104;
    int* histAll = wsi + 403456;
    int* curAll  = wsi + 491008;
    int* rpAll   = wsi + 578560;
    int* eidAll  = wsi + 666112;
    const size_t WfB = 1791232;
    float* WS[3] = {wsf + WfB, wsf + WfB + 32896, wsf + WfB + 65792};
    float* WN[3] = {wsf + WfB + 16384, wsf + WfB + 49280, wsf + WfB + 82176};
    float* BV[3] = {wsf + WfB + 32768, wsf + WfB + 65664, wsf + WfB + 98560};
    float* G0  = wsf + WfB + 98688;  float* BE0 = wsf + WfB + 98816;
    float* G1  = wsf + WfB + 98944;  float* BE1 = wsf + WfB + 99072;
    float* DW  = wsf + WfB + 99200;
    float* PW1 = wsf + WfB + 115584; float* PB1 = wsf + WfB + 131968;
    float* PW2 = wsf + WfB + 132096; float* PB2 = wsf + WfB + 148480;
    float* PW3 = wsf + WfB + 148608; float* PB3 = wsf + WfB + 148736;
    unsigned short* wfragL[3] = {(unsigned short*)(wsf + 1940480),
                                 (unsigned short*)(wsf + 1956864),
                                 (unsigned short*)(wsf + 1973248)};
    unsigned short* wfragP[2] = {(unsigned short*)(wsf + 1989632),
                                 (unsigned short*)(wsf + 1997824)};
    unsigned short* PF  = (unsigned short*)(wsf + 2006016);
    unsigned short* NF  = (unsigned short*)(wsf + 2806016);
    unsigned short* H2P = (unsigned short*)(wsf + 3606016);
    unsigned short* H2N = (unsigned short*)(wsf + 5206016);
    unsigned short* H1P = (unsigned short*)(wsf + 6806016);
    unsigned short* H1N = (unsigned short*)(wsf + 10006016);
    unsigned short* AGG = (unsigned short*)(wsf + 13206016);  // 50k rows; 100k if bigWS
    unsigned short* ZA = H1N;
    unsigned short* ZB = H1N + (size_t)2560000;

    // big-WS: single batched L0 (AGG = 100k rows => peak 78.4 MiB)
    const bool bigWS = ws_size >= (size_t)(13206016 + 6400000) * 4;

    // ---- dtype detect + weight conversion ----
    detect_dtype<<<1, 256, 0, stream>>>((const unsigned int*)x, flagp);
    CvtTable tab;
    const int widx[20] = {12,13,14, 15,16,17, 18,19,20, 21,22,23,24, 25, 26,27, 28,29, 30,31};
    float* wdst[20] = {WS[0],WN[0],BV[0], WS[1],WN[1],BV[1], WS[2],WN[2],BV[2],
                       G0,BE0,G1,BE1, DW, PW1,PB1, PW2,PB2, PW3,PB3};
    const int wn[20] = {16384,16384,128, 16384,16384,128, 16384,16384,128,
                        128,128,128,128, 16384, 16384,128, 16384,128, 128,1};
    int tot = 0;
    for (int k = 0; k < 20; ++k) {
        tab.src[k] = d_in[widx[k]];
        tab.off[k] = (int)(wdst[k] - wsf);
        tab.n[k] = wn[k];
        tot += wn[k];
    }
    tab.total = tot;
    cvt_all<<<(tot + 255) / 256, 256, 0, stream>>>(tab, wsf, flagp);

    // ---- CSR build ----
    hipMemsetAsync(histAll, 0, (size_t)(2 * NCAT + 128) * 4, stream);
    int Etot = E[0] + E[1] + E[2];
    hist_all<<<(Etot + 255) / 256, 256, 0, stream>>>(
        dstA[0], E[0], dstA[1], E[1], dstA[2], E[2], histAll);
    {
        int nb = (NCAT / 4 + 255) / 256;
        scan_bsum<<<nb, 256, 0, stream>>>(histAll, NCAT, bsums);
        scan_bscan<<<1, 256, 0, stream>>>(bsums, nb, rpAll + NCAT);
        scan_apply<<<nb, 256, 0, stream>>>(histAll, NCAT, bsums, rpAll);
    }
    csr_fill_win<<<512, 256, 0, stream>>>(
        srcA[0], dstA[0], E[0], srcA[1], dstA[1], E[1], srcA[2], dstA[2], E[2],
        rpAll, curAll, eidAll);

    // ---- MFMA W-fragment tables ----
    WfAll wa;
    wa.W1[0] = WS[0]; wa.W2[0] = WN[0]; wa.dst[0] = wfragL[0]; wa.KS[0] = 8; wa.start[0] = 0;
    wa.W1[1] = WS[1]; wa.W2[1] = WN[1]; wa.dst[1] = wfragL[1]; wa.KS[1] = 8; wa.start[1] = 4096;
    wa.W1[2] = WS[2]; wa.W2[2] = WN[2]; wa.dst[2] = wfragL[2]; wa.KS[2] = 8; wa.start[2] = 8192;
    wa.W1[3] = PW1;   wa.W2[3] = nullptr; wa.dst[3] = wfragP[0]; wa.KS[3] = 4; wa.start[3] = 12288;
    wa.W1[4] = PW2;   wa.W2[4] = nullptr; wa.dst[4] = wfragP[1]; wa.KS[4] = 4; wa.start[4] = 14336;
    wa.total = 16384;
    wfrag_all<<<64, 256, 0, stream>>>(wa);

    const int nb0 = (N1 + 63) / 64, nb1 = (N2 + 63) / 64, nb2 = (N3 + 63) / 64;

    // ===== layer 0 =====
    if (bigWS) {
        // both halves in one gather + one gemm
        gather2<<<(2 * N1 + 3) / 4, 256, 0, stream>>>(
            x, x, flagp, nullptr, perm, nullptr, nullptr, nullptr, nullptr,
            rpAll, eidAll, N1, 2 * N1, AGG);
        GHalf hP = {x, nullptr, nullptr, nullptr, AGG,                       H1P, PSP, PQP};
        GHalf hN = {x, perm,    nullptr, nullptr, AGG + (size_t)N1 * DD,     H1N, PSN, PQN};
        mfma_gemm2<<<2 * nb0, 256, 0, stream>>>(hP, hN, flagp, (const uint4*)wfragL[0], BV[0], N1, nb0);
    } else {
        gather2<<<(N1 + 3) / 4, 256, 0, stream>>>(
            x, x, flagp, nullptr, nullptr, nullptr, nullptr, nullptr, nullptr,
            rpAll, eidAll, N1, N1, AGG);
        {
            GHalf hP = {x, nullptr, nullptr, nullptr, AGG, H1P, PSP, PQP};
            mfma_gemm2<<<nb0, 256, 0, stream>>>(hP, hP, flagp, (const uint4*)wfragL[0], BV[0], N1, nb0);
        }
        gather2<<<(N1 + 3) / 4, 256, 0, stream>>>(
            x, x, flagp, perm, perm, nullptr, nullptr, nullptr, nullptr,
            rpAll, eidAll, N1, N1, AGG);
        {
            GHalf hN = {x, perm, nullptr, nullptr, AGG, H1N, PSN, PQN};
            mfma_gemm2<<<nb0, 256, 0, stream>>>(hN, hN, flagp, (const uint4*)wfragL[0], BV[0], N1, nb0);
        }
    }
    p2bn_fast<<<256, 256, 0, stream>>>(PSP, PQP, scP0, shP0, PSN, PQN, scN0, shN0, nb0, N1, G0, BE0);

    // ===== layer 1: batched gather (BN fold), one two-half gemm =====
    gather2<<<(2 * N2 + 3) / 4, 256, 0, stream>>>(
        H1P, H1N, nullptr, nullptr, nullptr, scP0, shP0, scN0, shN0,
        rpAll + 50000, eidAll, N2, 2 * N2, AGG);
    {
        GHalf hP = {H1P, nullptr, scP0, shP0, AGG,                      H2P, PSP, PQP};
        GHalf hN = {H1N, nullptr, scN0, shN0, AGG + (size_t)N2 * DD,    H2N, PSN, PQN};
        mfma_gemm2<<<2 * nb1, 256, 0, stream>>>(hP, hN, nullptr, (const uint4*)wfragL[1], BV[1], N2, nb1);
    }
    p2bn_fast<<<256, 256, 0, stream>>>(PSP, PQP, scP1, shP1, PSN, PQN, scN1, shN1, nb1, N2, G1, BE1);

    // ===== layer 2: batched gather (BN fold), one two-half gemm (P stats only) =====
    gather2<<<(2 * N3 + 3) / 4, 256, 0, stream>>>(
        H2P, H2N, nullptr, nullptr, nullptr, scP1, shP1, scN1, shN1,
        rpAll + 75000, eidAll, N3, 2 * N3, AGG);
    {
        GHalf hP = {H2P, nullptr, scP1, shP1, AGG,                      PF, PSP, PQP};
        GHalf hN = {H2N, nullptr, scN1, shN1, AGG + (size_t)N3 * DD,    NF, nullptr, nullptr};
        mfma_gemm2<<<2 * nb2, 256, 0, stream>>>(hP, hN, nullptr, (const uint4*)wfragL[2], BV[2], N3, nb2);
    }
    colreduce<<<128, 256, 0, stream>>>(PSP, nb2, colsum);
    make_ws<<<1, 128, 0, stream>>>(colsum, DW, wsvec, N3);

    // ===== discriminator loss =====
    loss_partial<<<NBLK, 256, 0, stream>>>(PF, NF, wsvec, lossP, lossN, N3);
    write_loss<<<1, 256, 0, stream>>>(lossP, lossN, d_out, N3, flagp);

    // ===== predictor MLP: pair-mult fused into gemm1 =====
    pred_gemm<<<(2 * EP + 63) / 64, 256, 0, stream>>>(
        nullptr, PF, pos_src, pos_dst, neg_src, neg_dst, EP,
        (const uint4*)wfragP[0], PB1, ZA, 2 * EP);
    pred_gemm<<<(2 * EP + 63) / 64, 256, 0, stream>>>(
        ZA, nullptr, nullptr, nullptr, nullptr, nullptr, 0,
        (const uint4*)wfragP[1], PB2, ZB, 2 * EP);
    final_mv<<<(2 * EP + 3) / 4, 256, 0, stream>>>(ZB, PW3, PB3, d_out, 2 * EP, flagp);
}